// Round 24
// baseline (67.712 us; speedup 1.0000x reference)
//
#include <hip/hip_runtime.h>
#include <math.h>

#define T 2048
#define E 64
#define H 8
#define B 2

typedef __attribute__((ext_vector_type(4))) float f32x4;
typedef __attribute__((ext_vector_type(8))) short s16x8;

static __device__ __forceinline__ unsigned short f2bf(float x) {
    union { float f; unsigned u; } v; v.f = x;
    unsigned r = v.u + 0x7FFFu + ((v.u >> 16) & 1u);   // RNE
    return (unsigned short)(r >> 16);
}
static __device__ __forceinline__ float bf2f(unsigned short u) {
    union { unsigned u; float f; } v; v.u = ((unsigned)u) << 16;
    return v.f;
}
// packed bf16 convert: low short = lo, high short = hi (RNE, HW cvt)
static __device__ __forceinline__ unsigned pk_bf16(float lo, float hi) {
    unsigned r;
    asm("v_cvt_pk_bf16_f32 %0, %1, %2" : "=v"(r) : "v"(lo), "v"(hi));
    return r;
}

// ---------------------------------------------------------------------------
// K1: block = (one head h, 64 tokens).  vk[h] staged ONCE into LDS transposed
// wkT[f][e] (+pad); emb tile in LDS; inner loop pure LDS+FMA.  (unchanged)
// ---------------------------------------------------------------------------
__global__ __launch_bounds__(256) void qkvT_kernel(
    const float* __restrict__ emb,   // [B,T,E]
    const float* __restrict__ qk,    // [H,E]
    const float* __restrict__ kk,    // [H,E]
    const float* __restrict__ vk,    // [H,E,E]
    float* __restrict__ qs,          // [B*H,T]
    float* __restrict__ ks,          // [B*H,T]
    unsigned short* __restrict__ vT) // [B*H,E(f),T] bf16
{
    int h  = blockIdx.x & 7;
    int tc = blockIdx.x >> 3;            // 0..63
    int b  = tc >> 5;
    int t0 = (tc & 31) * 64;
    int tid = threadIdx.x;

    __shared__ __align__(16) float eL[64][64];            // 16 KB
    __shared__ __align__(16) float wkT[64*68];            // [f][e] padded, 17.4 KB
    __shared__ __align__(16) unsigned short vtile[4096];  // [64 f][64 t] swz, 8 KB

    // stage emb tile (coalesced)
    #pragma unroll
    for (int i = 0; i < 4; ++i) {
        int s = tid + i*256;             // float4 slot 0..1023
        int t = s >> 4, e4 = s & 15;
        ((float4*)&eL[t][0])[e4] = ((const float4*)(emb + ((long)b*T + t0 + t)*E))[e4];
    }
    // stage vk[h] transposed -> wkT[f][e]  (read coalesced, scatter to LDS)
    const float* vkh = vk + h*4096;
    #pragma unroll
    for (int i = 0; i < 16; ++i) {
        int s = tid + i*256;
        int e = s >> 6, f = s & 63;
        wkT[f*68 + e] = vkh[e*64 + f];
    }
    __syncthreads();

    // scores: 64 tokens x {q,k} (128 dots of 64); +t stagger spreads banks
    if (tid < 128) {
        int t = tid & 63, sel = tid >> 6;
        const float* wp = (sel ? kk : qk) + h*64;
        float s = 0.f;
        #pragma unroll
        for (int e = 0; e < 64; ++e) {
            int ei = (e + t) & 63;
            s += eL[t][ei] * wp[ei];
        }
        float* dst = sel ? ks : qs;
        dst[((long)b*H + h)*T + t0 + t] = s;
    }

    // V projection: lane f = tid&63, wave wv = tid>>6 owns t-chunks wv, wv+4
    int f  = tid & 63;
    int wv = tid >> 6;
    float acc[2][8];
    #pragma unroll
    for (int hf2 = 0; hf2 < 2; ++hf2)
        #pragma unroll
        for (int i = 0; i < 8; ++i) acc[hf2][i] = 0.f;

    #pragma unroll 4
    for (int e4 = 0; e4 < 16; ++e4) {
        float4 w4 = *(const float4*)&wkT[f*68 + e4*4];   // per-lane f: spread
        #pragma unroll
        for (int half = 0; half < 2; ++half) {
            int tb = half*32 + wv*8;
            #pragma unroll
            for (int i = 0; i < 8; ++i) {
                float4 ev = *(const float4*)&eL[tb + i][e4*4];  // wave-uniform: broadcast
                acc[half][i] += ev.x*w4.x + ev.y*w4.y + ev.z*w4.z + ev.w*w4.w;
            }
        }
    }

    // pack -> swizzled vtile (b128, conflict-free)
    #pragma unroll
    for (int half = 0; half < 2; ++half) {
        int c = wv + half*4;             // t-chunk 0..7
        s16x8 o;
        #pragma unroll
        for (int i = 0; i < 8; ++i) o[i] = (short)f2bf(acc[half][i]);
        *(s16x8*)&vtile[f*64 + ((c ^ (f & 7)) * 8)] = o;
    }
    __syncthreads();

    // coalesced writeout: 8 lanes per f-row -> 128B contiguous
    long rowbase = ((long)(b*H + h)*64) * (long)T;
    #pragma unroll
    for (int i = 0; i < 2; ++i) {
        int s = tid + i*256;             // 0..511
        int fo = s >> 3, c = s & 7;
        s16x8 v = *(const s16x8*)&vtile[fo*64 + ((c ^ (fo & 7)) * 8)];
        *(s16x8*)(vT + rowbase + (long)fo*T + t0 + c*8) = v;
    }
}

// ---------------------------------------------------------------------------
// K3: attention via MFMA with K-SPLIT=2 (round-22 structure).  THIS ROUND:
//   pnum stored bf16 (halves the 32 MB partial round-trip).
// ---------------------------------------------------------------------------
__global__ __launch_bounds__(256) void attn_kernel(
    const float* __restrict__ qs, const float* __restrict__ ksg,
    const unsigned short* __restrict__ vT,
    unsigned short* __restrict__ pnum,  // [2*16][T][64] bf16 partial numerators
    float* __restrict__ pden)           // [2*16][T] fp32 partial denominators
{
    int bh   = blockIdx.x >> 6;          // 0..15
    int rest = blockIdx.x & 63;
    int q0   = (rest >> 1) * 64;
    int ksp  = rest & 1;                 // k-split half
    int tid = threadIdx.x;
    int w = tid >> 6, l = tid & 63;
    int g = l >> 4, r = l & 15;

    __shared__ __align__(16) float ksL[1024];              // own half, 4 KB
    __shared__ __align__(16) unsigned short VtL[2][8192];  // 2x[64 f][128 k] swz, 32 KB
    __shared__ float sMx[4], sMn[4];

    // full-row load for GLOBAL min/max; stage only own half to LDS
    float4 k0 = ((const float4*)(ksg + (long)bh*T))[tid];        // first half
    float4 k1 = ((const float4*)(ksg + (long)bh*T))[tid + 256];  // second half
    ((float4*)ksL)[tid] = ksp ? k1 : k0;

    float mx = fmaxf(fmaxf(fmaxf(k0.x, k0.y), fmaxf(k0.z, k0.w)),
                     fmaxf(fmaxf(k1.x, k1.y), fmaxf(k1.z, k1.w)));
    float mn = fminf(fminf(fminf(k0.x, k0.y), fminf(k0.z, k0.w)),
                     fminf(fminf(k1.x, k1.y), fminf(k1.z, k1.w)));
    #pragma unroll
    for (int o = 1; o < 64; o <<= 1) {
        mx = fmaxf(mx, __shfl_xor(mx, o, 64));
        mn = fminf(mn, __shfl_xor(mn, o, 64));
    }
    if (l == 0) { sMx[w] = mx; sMn[w] = mn; }

    float sreg = qs[(long)bh*T + q0 + w*16 + r];
    int kg0 = ksp * 8;                   // global chunk base

    // prologue: stage chunk kg0 into VtL[0]
    #pragma unroll
    for (int j = 0; j < 4; ++j) {
        int i = tid + j*256;             // 16B-slot 0..1023
        int f = i >> 4, si = i & 15;
        s16x8 val = *(const s16x8*)(vT + ((long)(bh*64 + f))*T + kg0*128 + si*8);
        *(s16x8*)&VtL[0][f*128 + ((si ^ (f & 15)) * 8)] = val;
    }
    __syncthreads();                     // ksL + chunk0 + sMx/sMn visible

    float kmx = fmaxf(fmaxf(sMx[0], sMx[1]), fmaxf(sMx[2], sMx[3]));
    float kmn = fminf(fminf(sMn[0], sMn[1]), fminf(sMn[2], sMn[3]));
    float mreg = (sreg >= 0.f) ? sreg*kmx : sreg*kmn;

    f32x4 acc[4] = {{0.f,0.f,0.f,0.f},{0.f,0.f,0.f,0.f},
                    {0.f,0.f,0.f,0.f},{0.f,0.f,0.f,0.f}};
    float dsum = 0.f;

    for (int kc = 0; kc < 8; ++kc) {
        int cur = kc & 1;
        // issue prefetch loads for next chunk (latency hides under compute)
        s16x8 pf[4];
        if (kc < 7) {
            #pragma unroll
            for (int j = 0; j < 4; ++j) {
                int i = tid + j*256;
                int f = i >> 4, si = i & 15;
                pf[j] = *(const s16x8*)(vT + ((long)(bh*64 + f))*T + (kg0 + kc + 1)*128 + si*8);
            }
        }
        // compute chunk kc from VtL[cur]
        #pragma unroll
        for (int kw = 0; kw < 4; ++kw) { // 32-k MFMA windows
            int kbase = kc*128 + kw*32 + g*8;    // LOCAL ksL index
            float4 ka = *(const float4*)&ksL[kbase & 1023];
            float4 kb = *(const float4*)&ksL[(kbase & 1023) + 4];
            float p0 = __expf(fmaf(sreg, ka.x, -mreg));
            float p1 = __expf(fmaf(sreg, ka.y, -mreg));
            float p2 = __expf(fmaf(sreg, ka.z, -mreg));
            float p3 = __expf(fmaf(sreg, ka.w, -mreg));
            float p4 = __expf(fmaf(sreg, kb.x, -mreg));
            float p5 = __expf(fmaf(sreg, kb.y, -mreg));
            float p6 = __expf(fmaf(sreg, kb.z, -mreg));
            float p7 = __expf(fmaf(sreg, kb.w, -mreg));
            dsum += ((p0+p1)+(p2+p3)) + ((p4+p5)+(p6+p7));
            union { s16x8 v; unsigned u[4]; } af;
            af.u[0] = pk_bf16(p0, p1);
            af.u[1] = pk_bf16(p2, p3);
            af.u[2] = pk_bf16(p4, p5);
            af.u[3] = pk_bf16(p6, p7);
            int slot = kw*4 + g;
            #pragma unroll
            for (int ct = 0; ct < 4; ++ct) {
                s16x8 bf = *(const s16x8*)&VtL[cur][(ct*16 + r)*128 + ((slot ^ r) * 8)];
                acc[ct] = __builtin_amdgcn_mfma_f32_16x16x32_bf16(af.v, bf, acc[ct], 0, 0, 0);
            }
        }
        // write prefetched chunk to the other buffer
        if (kc < 7) {
            #pragma unroll
            for (int j = 0; j < 4; ++j) {
                int i = tid + j*256;
                int f = i >> 4, si = i & 15;
                *(s16x8*)&VtL[cur ^ 1][f*128 + ((si ^ (f & 15)) * 8)] = pf[j];
            }
        }
        __syncthreads();                 // next-chunk staging visible
    }

    // partial row-denominator: reduce over the 4 k-slot groups
    dsum += __shfl_xor(dsum, 16, 64);
    dsum += __shfl_xor(dsum, 32, 64);

    long pbase = ((long)(ksp*16 + bh)) * T;
    if (l < 16) pden[pbase + q0 + w*16 + l] = dsum;   // lane l holds row w*16+l

    #pragma unroll
    for (int i = 0; i < 4; ++i) {
        int lrow = g*4 + i;               // C layout: local row=(lane>>4)*4+i
        long q = q0 + w*16 + lrow;
        #pragma unroll
        for (int ct = 0; ct < 4; ++ct)
            pnum[(pbase + q)*64 + ct*16 + r] = f2bf(acc[ct][i]);
    }
}

// ---------------------------------------------------------------------------
// K4a: combine k-split partials (bf16) + residual + LN1 -> Zb bf16.
// ---------------------------------------------------------------------------
__global__ __launch_bounds__(256) void ln1_kernel(
    const float* __restrict__ emb,
    const unsigned short* __restrict__ pnum, const float* __restrict__ pden,
    const float* __restrict__ g1, const float* __restrict__ b1,
    unsigned short* __restrict__ Zb) // [B*T,512] bf16
{
    int row  = blockIdx.x*4 + (threadIdx.x >> 6);  // bh*T + t, 0..32767
    int lane = threadIdx.x & 63;
    int bh = row >> 11, t = row & 2047;
    int b = bh >> 3, h = bh & 7;
    long i0 = ((long)bh)*T + t;          // split-0 row
    long i1 = ((long)(16 + bh))*T + t;   // split-1 row
    float n = bf2f(pnum[i0*64 + lane]) + bf2f(pnum[i1*64 + lane]);
    float d = pden[i0] + pden[i1];
    float x = emb[((long)b*T + t)*64 + lane] + n / d;

    float s = x, s2 = x*x;
    #pragma unroll
    for (int o = 1; o < 64; o <<= 1) {
        s  += __shfl_xor(s,  o, 64);
        s2 += __shfl_xor(s2, o, 64);
    }
    float mu  = s * (1.f/64.f);
    float var = s2 * (1.f/64.f) - mu*mu;
    float rs  = rsqrtf(var + 1e-3f);
    float zn  = g1[lane]*(x - mu)*rs + b1[lane];
    Zb[((long)b*T + t)*512 + h*64 + lane] = f2bf(zn);
}

// ---------------------------------------------------------------------------
// K4b: weight transpose+cast: fk[h,g,e,f] fp32 -> WbT[n=g*64+f][k=h*64+e] bf16
// ---------------------------------------------------------------------------
__global__ __launch_bounds__(256) void wcvt_kernel(
    const float* __restrict__ fk, unsigned short* __restrict__ WbT)
{
    int hg = blockIdx.x;                 // h*8+g
    int h = hg >> 3, g = hg & 7;
    int tid = threadIdx.x;
    __shared__ float wt[64][65];         // padded, 16.6 KB
    const float* src = fk + (long)hg*4096;
    #pragma unroll
    for (int j = 0; j < 4; ++j) {
        int s = tid + j*256;             // float4 slot 0..1023
        int e = s >> 4, f4 = s & 15;
        float4 v = ((const float4*)src)[s];
        wt[e][f4*4+0] = v.x; wt[e][f4*4+1] = v.y;
        wt[e][f4*4+2] = v.z; wt[e][f4*4+3] = v.w;
    }
    __syncthreads();
    #pragma unroll
    for (int j = 0; j < 2; ++j) {
        int s = tid + j*256;             // 16B slot 0..511
        int f = s >> 3, e8 = s & 7;
        s16x8 o;
        #pragma unroll
        for (int q = 0; q < 8; ++q) o[q] = (short)f2bf(wt[e8*8+q][f]);
        *(s16x8*)(WbT + ((long)(g*64+f))*512 + h*64 + e8*8) = o;
    }
}

// ---------------------------------------------------------------------------
// K4c: FFN GEMM via MFMA — double-buffered staging + smem-reuse epilogue
// (round-23 measured, unchanged).
// ---------------------------------------------------------------------------
__global__ __launch_bounds__(256) void ffn_gemm_kernel(
    const unsigned short* __restrict__ Zb,   // [4096][512] bf16
    const unsigned short* __restrict__ WbT,  // [512 n][512 k] bf16
    const float* __restrict__ g2, const float* __restrict__ b2,
    float* __restrict__ out)                 // [B,G,T,F]
{
    int bm = blockIdx.x >> 3;            // 0..63 token block
    int g  = blockIdx.x & 7;             // output head block
    int m0 = bm*64;
    int tid = threadIdx.x;
    int w = tid >> 6, l = tid & 63;
    int lg = l >> 4, r = l & 15;
    int wr = w >> 1, wc = w & 1;

    __shared__ __align__(16) char smem[32768];             // As[2]|Bs[2]; yL reuses
    unsigned short* As = (unsigned short*)smem;            // [2][4096]
    unsigned short* Bs = (unsigned short*)(smem + 16384);  // [2][4096]

    int sc16 = tid & 7;                  // staging col-chunk (fixed per thread)
    int srow0 = tid >> 3;                // staging rows (j=0: 0..31, j=1: 32..63)
    int srow1 = (tid + 256) >> 3;

    f32x4 acc[2][2] = {{{0.f,0.f,0.f,0.f},{0.f,0.f,0.f,0.f}},
                       {{0.f,0.f,0.f,0.f},{0.f,0.f,0.f,0.f}}};

    // prologue: stage kc=0 into buffer 0
    {
        s16x8 va0 = *(const s16x8*)(Zb  + ((long)(m0 + srow0))*512   + sc16*8);
        s16x8 vb0 = *(const s16x8*)(WbT + ((long)(g*64 + srow0))*512 + sc16*8);
        s16x8 va1 = *(const s16x8*)(Zb  + ((long)(m0 + srow1))*512   + sc16*8);
        s16x8 vb1 = *(const s16x8*)(WbT + ((long)(g*64 + srow1))*512 + sc16*8);
        *(s16x8*)&As[srow0*64 + ((sc16 ^ (srow0 & 7))*8)] = va0;
        *(s16x8*)&Bs[srow0*64 + ((sc16 ^ (srow0 & 7))*8)] = vb0;
        *(s16x8*)&As[srow1*64 + ((sc16 ^ (srow1 & 7))*8)] = va1;
        *(s16x8*)&Bs[srow1*64 + ((sc16 ^ (srow1 & 7))*8)] = vb1;
    }
    __syncthreads();

    for (int kc = 0; kc < 8; ++kc) {
        int cur = kc & 1;
        // prefetch next K-tile into registers (hides under compute)
        s16x8 pva0, pvb0, pva1, pvb1;
        if (kc < 7) {
            pva0 = *(const s16x8*)(Zb  + ((long)(m0 + srow0))*512   + (kc+1)*64 + sc16*8);
            pvb0 = *(const s16x8*)(WbT + ((long)(g*64 + srow0))*512 + (kc+1)*64 + sc16*8);
            pva1 = *(const s16x8*)(Zb  + ((long)(m0 + srow1))*512   + (kc+1)*64 + sc16*8);
            pvb1 = *(const s16x8*)(WbT + ((long)(g*64 + srow1))*512 + (kc+1)*64 + sc16*8);
        }
        #pragma unroll
        for (int kk = 0; kk < 2; ++kk) {
            s16x8 af[2], bf[2];
            #pragma unroll
            for (int mi = 0; mi < 2; ++mi) {
                int row = wr*32 + mi*16 + r;
                af[mi] = *(const s16x8*)&As[cur*4096 + row*64 + (((kk*4 + lg) ^ (row & 7))*8)];
            }
            #pragma unroll
            for (int ni = 0; ni < 2; ++ni) {
                int row = wc*32 + ni*16 + r;
                bf[ni] = *(const s16x8*)&Bs[cur*4096 + row*64 + (((kk*4 + lg) ^ (row & 7))*8)];
            }
            #pragma unroll
            for (int mi = 0; mi < 2; ++mi)
                #pragma unroll
                for (int ni = 0; ni < 2; ++ni)
                    acc[mi][ni] = __builtin_amdgcn_mfma_f32_16x16x32_bf16(
                        af[mi], bf[ni], acc[mi][ni], 0, 0, 0);
        }
        if (kc < 7) {
            int nb = (cur ^ 1) * 4096;
            *(s16x8*)&As[nb + srow0*64 + ((sc16 ^ (srow0 & 7))*8)] = pva0;
            *(s16x8*)&Bs[nb + srow0*64 + ((sc16 ^ (srow0 & 7))*8)] = pvb0;
            *(s16x8*)&As[nb + srow1*64 + ((sc16 ^ (srow1 & 7))*8)] = pva1;
            *(s16x8*)&Bs[nb + srow1*64 + ((sc16 ^ (srow1 & 7))*8)] = pvb1;
        }
        __syncthreads();
    }
    // all As/Bs reads complete (final barrier above) -> reuse smem as yL
    float (*yL)[68] = (float(*)[68])smem;              // 64x68 fp32, 17.4 KB

    // scatter C to yL (C layout: col=lane&15, row=(lane>>4)*4+i)
    #pragma unroll
    for (int mi = 0; mi < 2; ++mi)
        #pragma unroll
        for (int ni = 0; ni < 2; ++ni)
            #pragma unroll
            for (int i = 0; i < 4; ++i)
                yL[wr*32 + mi*16 + lg*4 + i][wc*32 + ni*16 + r] = acc[mi][ni][i];
    __syncthreads();

    // residual + gelu + LN2: quad of lanes per token row (4 x 16 elems)
    int rowt = tid >> 2, part = tid & 3;
    const unsigned short* zrow = Zb + ((long)(m0 + rowt))*512 + g*64 + part*16;
    s16x8 z0 = *(const s16x8*)zrow;
    s16x8 z1 = *(const s16x8*)(zrow + 8);
    const float kg = 0.7978845608028654f;
    float y[16];
    float s = 0.f, s2 = 0.f;
    #pragma unroll
    for (int q = 0; q < 16; ++q) {
        float zn = bf2f((unsigned short)(q < 8 ? z0[q] : z1[q-8]));
        float x = zn + yL[rowt][part*16 + q];
        x = 0.5f*x*(1.f + tanhf(kg*(x + 0.044715f*x*x*x)));
        y[q] = x; s += x; s2 += x*x;
    }
    s  += __shfl_xor(s,  1, 64);  s  += __shfl_xor(s,  2, 64);
    s2 += __shfl_xor(s2, 1, 64);  s2 += __shfl_xor(s2, 2, 64);
    float mu  = s * (1.f/64.f);
    float var = s2 * (1.f/64.f) - mu*mu;
    float rs  = rsqrtf(var + 1e-3f);

    int token = m0 + rowt;
    int b = token >> 11, t = token & 2047;
    long ob = (((long)(b*H + g))*T + t)*64 + part*16;
    #pragma unroll
    for (int q = 0; q < 16; ++q) {
        int f = part*16 + q;
        y[q] = g2[f]*(y[q] - mu)*rs + b2[f];
    }
    #pragma unroll
    for (int q = 0; q < 4; ++q) {
        float4 o = { y[q*4], y[q*4+1], y[q*4+2], y[q*4+3] };
        *(float4*)(out + ob + q*4) = o;
    }
}

// ---------------------------------------------------------------------------
extern "C" void kernel_launch(void* const* d_in, const int* in_sizes, int n_in,
                              void* d_out, int out_size, void* d_ws, size_t ws_size,
                              hipStream_t stream) {
    const float* emb  = (const float*)d_in[0];
    const float* keyk = (const float*)d_in[1];
    const float* qryk = (const float*)d_in[2];
    const float* valk = (const float*)d_in[3];
    const float* ffk  = (const float*)d_in[4];
    const float* g1   = (const float*)d_in[5];
    const float* b1   = (const float*)d_in[6];
    const float* g2   = (const float*)d_in[7];
    const float* b2   = (const float*)d_in[8];
    float* out = (float*)d_out;

    float* ws   = (float*)d_ws;
    float* qs   = ws;                         // 32768 floats
    float* ks   = ws + 32768;                 // 32768
    unsigned short* vT = (unsigned short*)(ws + 65568);   // 2,097,152 bf16 (1,048,576 slots)
    unsigned short* pnum = (unsigned short*)(ws + 65568 + 1048576); // 4,194,304 bf16 (2,097,152 slots)
    float* pden = ws + 65568 + 1048576 + 2097152;         // 65,536 floats
    // Zb OVERLAYS vT: vT is dead after attn_kernel; stream order makes this
    // deterministic (qkvT writes vT -> attn reads vT -> ln1 overwrites as Zb).
    unsigned short* Zb  = vT;                 // 2,097,152 bf16
    unsigned short* WbT = (unsigned short*)(pden + 65536); // 262,144 bf16

    qkvT_kernel<<<(B*T/64)*H, 256, 0, stream>>>(emb, qryk, keyk, valk, qs, ks, vT);
    attn_kernel<<<B*H*(T/64)*2, 256, 0, stream>>>(qs, ks, vT, pnum, pden);
    ln1_kernel<<<B*H*T/4, 256, 0, stream>>>(emb, pnum, pden, g1, b1, Zb);
    wcvt_kernel<<<H*H, 256, 0, stream>>>(ffk, WbT);
    ffn_gemm_kernel<<<(B*T/64)*H, 256, 0, stream>>>(Zb, WbT, g2, b2, out);
}

// Round 25
// 65.518 us; speedup vs baseline: 1.0335x; 1.0335x over previous
//
#include <hip/hip_runtime.h>
#include <math.h>

#define T 2048
#define E 64
#define H 8
#define B 2

typedef __attribute__((ext_vector_type(4))) float f32x4;
typedef __attribute__((ext_vector_type(8))) short s16x8;

static __device__ __forceinline__ unsigned short f2bf(float x) {
    union { float f; unsigned u; } v; v.f = x;
    unsigned r = v.u + 0x7FFFu + ((v.u >> 16) & 1u);   // RNE
    return (unsigned short)(r >> 16);
}
static __device__ __forceinline__ float bf2f(unsigned short u) {
    union { unsigned u; float f; } v; v.u = ((unsigned)u) << 16;
    return v.f;
}
// packed bf16 convert: low short = lo, high short = hi (RNE, HW cvt)
static __device__ __forceinline__ unsigned pk_bf16(float lo, float hi) {
    unsigned r;
    asm("v_cvt_pk_bf16_f32 %0, %1, %2" : "=v"(r) : "v"(lo), "v"(hi));
    return r;
}

// ---------------------------------------------------------------------------
// K1 (FUSED): blocks 0..511 = qkvT (one head, 64 tokens); blocks 512..575 =
// weight transpose+cast (was wcvt_kernel).  One dispatch fewer; both branches
// are per-block uniform (no divergent barriers); smem carved from one arena.
// ---------------------------------------------------------------------------
__global__ __launch_bounds__(256) void qkvT_kernel(
    const float* __restrict__ emb,   // [B,T,E]
    const float* __restrict__ qk,    // [H,E]
    const float* __restrict__ kk,    // [H,E]
    const float* __restrict__ vk,    // [H,E,E]
    const float* __restrict__ fk,    // [H,G,E,F]
    float* __restrict__ qs,          // [B*H,T]
    float* __restrict__ ks,          // [B*H,T]
    unsigned short* __restrict__ vT, // [B*H,E(f),T] bf16
    unsigned short* __restrict__ WbT)// [512 n][512 k] bf16
{
    __shared__ __align__(16) char smem[41984];  // qkvT: eL|wkT|vtile; wcvt: wt
    int tid = threadIdx.x;

    if (blockIdx.x >= 512) {
        // ---- weight transpose+cast branch (identical math to old wcvt) ----
        int hg = blockIdx.x - 512;       // h*8+g
        int h = hg >> 3, g = hg & 7;
        float (*wt)[65] = (float(*)[65])smem;   // 16.6 KB
        const float* src = fk + (long)hg*4096;
        #pragma unroll
        for (int j = 0; j < 4; ++j) {
            int s = tid + j*256;         // float4 slot 0..1023
            int e = s >> 4, f4 = s & 15;
            float4 v = ((const float4*)src)[s];
            wt[e][f4*4+0] = v.x; wt[e][f4*4+1] = v.y;
            wt[e][f4*4+2] = v.z; wt[e][f4*4+3] = v.w;
        }
        __syncthreads();
        #pragma unroll
        for (int j = 0; j < 2; ++j) {
            int s = tid + j*256;         // 16B slot 0..511
            int f = s >> 3, e8 = s & 7;
            s16x8 o;
            #pragma unroll
            for (int q = 0; q < 8; ++q) o[q] = (short)f2bf(wt[e8*8+q][f]);
            *(s16x8*)(WbT + ((long)(g*64+f))*512 + h*64 + e8*8) = o;
        }
        return;
    }

    // ---- qkvT branch (identical math to round-23 qkvT) ----
    int h  = blockIdx.x & 7;
    int tc = blockIdx.x >> 3;            // 0..63
    int b  = tc >> 5;
    int t0 = (tc & 31) * 64;

    float (*eL)[64] = (float(*)[64])smem;                         // 16 KB
    float* wkT = (float*)(smem + 16384);                          // 17.4 KB
    unsigned short* vtile = (unsigned short*)(smem + 16384 + 17408); // 8 KB

    // stage emb tile (coalesced)
    #pragma unroll
    for (int i = 0; i < 4; ++i) {
        int s = tid + i*256;             // float4 slot 0..1023
        int t = s >> 4, e4 = s & 15;
        ((float4*)&eL[t][0])[e4] = ((const float4*)(emb + ((long)b*T + t0 + t)*E))[e4];
    }
    // stage vk[h] transposed -> wkT[f][e]  (read coalesced, scatter to LDS)
    const float* vkh = vk + h*4096;
    #pragma unroll
    for (int i = 0; i < 16; ++i) {
        int s = tid + i*256;
        int e = s >> 6, f = s & 63;
        wkT[f*68 + e] = vkh[e*64 + f];
    }
    __syncthreads();

    // scores: 64 tokens x {q,k} (128 dots of 64); +t stagger spreads banks
    if (tid < 128) {
        int t = tid & 63, sel = tid >> 6;
        const float* wp = (sel ? kk : qk) + h*64;
        float s = 0.f;
        #pragma unroll
        for (int e = 0; e < 64; ++e) {
            int ei = (e + t) & 63;
            s += eL[t][ei] * wp[ei];
        }
        float* dst = sel ? ks : qs;
        dst[((long)b*H + h)*T + t0 + t] = s;
    }

    // V projection: lane f = tid&63, wave wv = tid>>6 owns t-chunks wv, wv+4
    int f  = tid & 63;
    int wv = tid >> 6;
    float acc[2][8];
    #pragma unroll
    for (int hf2 = 0; hf2 < 2; ++hf2)
        #pragma unroll
        for (int i = 0; i < 8; ++i) acc[hf2][i] = 0.f;

    #pragma unroll 4
    for (int e4 = 0; e4 < 16; ++e4) {
        float4 w4 = *(const float4*)&wkT[f*68 + e4*4];   // per-lane f: spread
        #pragma unroll
        for (int half = 0; half < 2; ++half) {
            int tb = half*32 + wv*8;
            #pragma unroll
            for (int i = 0; i < 8; ++i) {
                float4 ev = *(const float4*)&eL[tb + i][e4*4];  // wave-uniform: broadcast
                acc[half][i] += ev.x*w4.x + ev.y*w4.y + ev.z*w4.z + ev.w*w4.w;
            }
        }
    }

    // pack -> swizzled vtile (b128, conflict-free)
    #pragma unroll
    for (int half = 0; half < 2; ++half) {
        int c = wv + half*4;             // t-chunk 0..7
        s16x8 o;
        #pragma unroll
        for (int i = 0; i < 8; ++i) o[i] = (short)f2bf(acc[half][i]);
        *(s16x8*)&vtile[f*64 + ((c ^ (f & 7)) * 8)] = o;
    }
    __syncthreads();

    // coalesced writeout: 8 lanes per f-row -> 128B contiguous
    long rowbase = ((long)(b*H + h)*64) * (long)T;
    #pragma unroll
    for (int i = 0; i < 2; ++i) {
        int s = tid + i*256;             // 0..511
        int fo = s >> 3, c = s & 7;
        s16x8 v = *(const s16x8*)&vtile[fo*64 + ((c ^ (fo & 7)) * 8)];
        *(s16x8*)(vT + rowbase + (long)fo*T + t0 + c*8) = v;
    }
}

// ---------------------------------------------------------------------------
// K3: attention via MFMA with K-SPLIT=2 (round-23 measured, fp32 pnum).
// ---------------------------------------------------------------------------
__global__ __launch_bounds__(256) void attn_kernel(
    const float* __restrict__ qs, const float* __restrict__ ksg,
    const unsigned short* __restrict__ vT,
    float* __restrict__ pnum,    // [2*16][T][64] fp32 partial numerators
    float* __restrict__ pden)    // [2*16][T] fp32 partial denominators
{
    int bh   = blockIdx.x >> 6;          // 0..15
    int rest = blockIdx.x & 63;
    int q0   = (rest >> 1) * 64;
    int ksp  = rest & 1;                 // k-split half
    int tid = threadIdx.x;
    int w = tid >> 6, l = tid & 63;
    int g = l >> 4, r = l & 15;

    __shared__ __align__(16) float ksL[1024];              // own half, 4 KB
    __shared__ __align__(16) unsigned short VtL[2][8192];  // 2x[64 f][128 k] swz, 32 KB
    __shared__ float sMx[4], sMn[4];

    // full-row load for GLOBAL min/max; stage only own half to LDS
    float4 k0 = ((const float4*)(ksg + (long)bh*T))[tid];        // first half
    float4 k1 = ((const float4*)(ksg + (long)bh*T))[tid + 256];  // second half
    ((float4*)ksL)[tid] = ksp ? k1 : k0;

    float mx = fmaxf(fmaxf(fmaxf(k0.x, k0.y), fmaxf(k0.z, k0.w)),
                     fmaxf(fmaxf(k1.x, k1.y), fmaxf(k1.z, k1.w)));
    float mn = fminf(fminf(fminf(k0.x, k0.y), fminf(k0.z, k0.w)),
                     fminf(fminf(k1.x, k1.y), fminf(k1.z, k1.w)));
    #pragma unroll
    for (int o = 1; o < 64; o <<= 1) {
        mx = fmaxf(mx, __shfl_xor(mx, o, 64));
        mn = fminf(mn, __shfl_xor(mn, o, 64));
    }
    if (l == 0) { sMx[w] = mx; sMn[w] = mn; }

    float sreg = qs[(long)bh*T + q0 + w*16 + r];
    int kg0 = ksp * 8;                   // global chunk base

    // prologue: stage chunk kg0 into VtL[0]
    #pragma unroll
    for (int j = 0; j < 4; ++j) {
        int i = tid + j*256;             // 16B-slot 0..1023
        int f = i >> 4, si = i & 15;
        s16x8 val = *(const s16x8*)(vT + ((long)(bh*64 + f))*T + kg0*128 + si*8);
        *(s16x8*)&VtL[0][f*128 + ((si ^ (f & 15)) * 8)] = val;
    }
    __syncthreads();                     // ksL + chunk0 + sMx/sMn visible

    float kmx = fmaxf(fmaxf(sMx[0], sMx[1]), fmaxf(sMx[2], sMx[3]));
    float kmn = fminf(fminf(sMn[0], sMn[1]), fminf(sMn[2], sMn[3]));
    float mreg = (sreg >= 0.f) ? sreg*kmx : sreg*kmn;

    f32x4 acc[4] = {{0.f,0.f,0.f,0.f},{0.f,0.f,0.f,0.f},
                    {0.f,0.f,0.f,0.f},{0.f,0.f,0.f,0.f}};
    float dsum = 0.f;

    for (int kc = 0; kc < 8; ++kc) {
        int cur = kc & 1;
        // issue prefetch loads for next chunk (latency hides under compute)
        s16x8 pf[4];
        if (kc < 7) {
            #pragma unroll
            for (int j = 0; j < 4; ++j) {
                int i = tid + j*256;
                int f = i >> 4, si = i & 15;
                pf[j] = *(const s16x8*)(vT + ((long)(bh*64 + f))*T + (kg0 + kc + 1)*128 + si*8);
            }
        }
        // compute chunk kc from VtL[cur]
        #pragma unroll
        for (int kw = 0; kw < 4; ++kw) { // 32-k MFMA windows
            int kbase = kc*128 + kw*32 + g*8;    // LOCAL ksL index
            float4 ka = *(const float4*)&ksL[kbase & 1023];
            float4 kb = *(const float4*)&ksL[(kbase & 1023) + 4];
            float p0 = __expf(fmaf(sreg, ka.x, -mreg));
            float p1 = __expf(fmaf(sreg, ka.y, -mreg));
            float p2 = __expf(fmaf(sreg, ka.z, -mreg));
            float p3 = __expf(fmaf(sreg, ka.w, -mreg));
            float p4 = __expf(fmaf(sreg, kb.x, -mreg));
            float p5 = __expf(fmaf(sreg, kb.y, -mreg));
            float p6 = __expf(fmaf(sreg, kb.z, -mreg));
            float p7 = __expf(fmaf(sreg, kb.w, -mreg));
            dsum += ((p0+p1)+(p2+p3)) + ((p4+p5)+(p6+p7));
            union { s16x8 v; unsigned u[4]; } af;
            af.u[0] = pk_bf16(p0, p1);
            af.u[1] = pk_bf16(p2, p3);
            af.u[2] = pk_bf16(p4, p5);
            af.u[3] = pk_bf16(p6, p7);
            int slot = kw*4 + g;
            #pragma unroll
            for (int ct = 0; ct < 4; ++ct) {
                s16x8 bf = *(const s16x8*)&VtL[cur][(ct*16 + r)*128 + ((slot ^ r) * 8)];
                acc[ct] = __builtin_amdgcn_mfma_f32_16x16x32_bf16(af.v, bf, acc[ct], 0, 0, 0);
            }
        }
        // write prefetched chunk to the other buffer
        if (kc < 7) {
            #pragma unroll
            for (int j = 0; j < 4; ++j) {
                int i = tid + j*256;
                int f = i >> 4, si = i & 15;
                *(s16x8*)&VtL[cur ^ 1][f*128 + ((si ^ (f & 15)) * 8)] = pf[j];
            }
        }
        __syncthreads();                 // next-chunk staging visible
    }

    // partial row-denominator: reduce over the 4 k-slot groups
    dsum += __shfl_xor(dsum, 16, 64);
    dsum += __shfl_xor(dsum, 32, 64);

    long pbase = ((long)(ksp*16 + bh)) * T;
    if (l < 16) pden[pbase + q0 + w*16 + l] = dsum;   // lane l holds row w*16+l

    #pragma unroll
    for (int i = 0; i < 4; ++i) {
        int lrow = g*4 + i;               // C layout: local row=(lane>>4)*4+i
        long q = q0 + w*16 + lrow;
        #pragma unroll
        for (int ct = 0; ct < 4; ++ct)
            pnum[(pbase + q)*64 + ct*16 + r] = acc[ct][i];
    }
}

// ---------------------------------------------------------------------------
// K4a: combine k-split partials + residual + LN1 -> Zb bf16 (GEMM layout).
// ---------------------------------------------------------------------------
__global__ __launch_bounds__(256) void ln1_kernel(
    const float* __restrict__ emb,
    const float* __restrict__ pnum, const float* __restrict__ pden,
    const float* __restrict__ g1, const float* __restrict__ b1,
    unsigned short* __restrict__ Zb) // [B*T,512] bf16
{
    int row  = blockIdx.x*4 + (threadIdx.x >> 6);  // bh*T + t, 0..32767
    int lane = threadIdx.x & 63;
    int bh = row >> 11, t = row & 2047;
    int b = bh >> 3, h = bh & 7;
    long i0 = ((long)bh)*T + t;          // split-0 row
    long i1 = ((long)(16 + bh))*T + t;   // split-1 row
    float n = pnum[i0*64 + lane] + pnum[i1*64 + lane];
    float d = pden[i0] + pden[i1];
    float x = emb[((long)b*T + t)*64 + lane] + n / d;

    float s = x, s2 = x*x;
    #pragma unroll
    for (int o = 1; o < 64; o <<= 1) {
        s  += __shfl_xor(s,  o, 64);
        s2 += __shfl_xor(s2, o, 64);
    }
    float mu  = s * (1.f/64.f);
    float var = s2 * (1.f/64.f) - mu*mu;
    float rs  = rsqrtf(var + 1e-3f);
    float zn  = g1[lane]*(x - mu)*rs + b1[lane];
    Zb[((long)b*T + t)*512 + h*64 + lane] = f2bf(zn);
}

// ---------------------------------------------------------------------------
// K4c: FFN GEMM via MFMA — double-buffered staging + smem-reuse epilogue
// (round-23 measured, unchanged).
// ---------------------------------------------------------------------------
__global__ __launch_bounds__(256) void ffn_gemm_kernel(
    const unsigned short* __restrict__ Zb,   // [4096][512] bf16
    const unsigned short* __restrict__ WbT,  // [512 n][512 k] bf16
    const float* __restrict__ g2, const float* __restrict__ b2,
    float* __restrict__ out)                 // [B,G,T,F]
{
    int bm = blockIdx.x >> 3;            // 0..63 token block
    int g  = blockIdx.x & 7;             // output head block
    int m0 = bm*64;
    int tid = threadIdx.x;
    int w = tid >> 6, l = tid & 63;
    int lg = l >> 4, r = l & 15;
    int wr = w >> 1, wc = w & 1;

    __shared__ __align__(16) char smem[32768];             // As[2]|Bs[2]; yL reuses
    unsigned short* As = (unsigned short*)smem;            // [2][4096]
    unsigned short* Bs = (unsigned short*)(smem + 16384);  // [2][4096]

    int sc16 = tid & 7;                  // staging col-chunk (fixed per thread)
    int srow0 = tid >> 3;                // staging rows (j=0: 0..31, j=1: 32..63)
    int srow1 = (tid + 256) >> 3;

    f32x4 acc[2][2] = {{{0.f,0.f,0.f,0.f},{0.f,0.f,0.f,0.f}},
                       {{0.f,0.f,0.f,0.f},{0.f,0.f,0.f,0.f}}};

    // prologue: stage kc=0 into buffer 0
    {
        s16x8 va0 = *(const s16x8*)(Zb  + ((long)(m0 + srow0))*512   + sc16*8);
        s16x8 vb0 = *(const s16x8*)(WbT + ((long)(g*64 + srow0))*512 + sc16*8);
        s16x8 va1 = *(const s16x8*)(Zb  + ((long)(m0 + srow1))*512   + sc16*8);
        s16x8 vb1 = *(const s16x8*)(WbT + ((long)(g*64 + srow1))*512 + sc16*8);
        *(s16x8*)&As[srow0*64 + ((sc16 ^ (srow0 & 7))*8)] = va0;
        *(s16x8*)&Bs[srow0*64 + ((sc16 ^ (srow0 & 7))*8)] = vb0;
        *(s16x8*)&As[srow1*64 + ((sc16 ^ (srow1 & 7))*8)] = va1;
        *(s16x8*)&Bs[srow1*64 + ((sc16 ^ (srow1 & 7))*8)] = vb1;
    }
    __syncthreads();

    for (int kc = 0; kc < 8; ++kc) {
        int cur = kc & 1;
        // prefetch next K-tile into registers (hides under compute)
        s16x8 pva0, pvb0, pva1, pvb1;
        if (kc < 7) {
            pva0 = *(const s16x8*)(Zb  + ((long)(m0 + srow0))*512   + (kc+1)*64 + sc16*8);
            pvb0 = *(const s16x8*)(WbT + ((long)(g*64 + srow0))*512 + (kc+1)*64 + sc16*8);
            pva1 = *(const s16x8*)(Zb  + ((long)(m0 + srow1))*512   + (kc+1)*64 + sc16*8);
            pvb1 = *(const s16x8*)(WbT + ((long)(g*64 + srow1))*512 + (kc+1)*64 + sc16*8);
        }
        #pragma unroll
        for (int kk = 0; kk < 2; ++kk) {
            s16x8 af[2], bf[2];
            #pragma unroll
            for (int mi = 0; mi < 2; ++mi) {
                int row = wr*32 + mi*16 + r;
                af[mi] = *(const s16x8*)&As[cur*4096 + row*64 + (((kk*4 + lg) ^ (row & 7))*8)];
            }
            #pragma unroll
            for (int ni = 0; ni < 2; ++ni) {
                int row = wc*32 + ni*16 + r;
                bf[ni] = *(const s16x8*)&Bs[cur*4096 + row*64 + (((kk*4 + lg) ^ (row & 7))*8)];
            }
            #pragma unroll
            for (int mi = 0; mi < 2; ++mi)
                #pragma unroll
                for (int ni = 0; ni < 2; ++ni)
                    acc[mi][ni] = __builtin_amdgcn_mfma_f32_16x16x32_bf16(
                        af[mi], bf[ni], acc[mi][ni], 0, 0, 0);
        }
        if (kc < 7) {
            int nb = (cur ^ 1) * 4096;
            *(s16x8*)&As[nb + srow0*64 + ((sc16 ^ (srow0 & 7))*8)] = pva0;
            *(s16x8*)&Bs[nb + srow0*64 + ((sc16 ^ (srow0 & 7))*8)] = pvb0;
            *(s16x8*)&As[nb + srow1*64 + ((sc16 ^ (srow1 & 7))*8)] = pva1;
            *(s16x8*)&Bs[nb + srow1*64 + ((sc16 ^ (srow1 & 7))*8)] = pvb1;
        }
        __syncthreads();
    }
    // all As/Bs reads complete (final barrier above) -> reuse smem as yL
    float (*yL)[68] = (float(*)[68])smem;              // 64x68 fp32, 17.4 KB

    // scatter C to yL (C layout: col=lane&15, row=(lane>>4)*4+i)
    #pragma unroll
    for (int mi = 0; mi < 2; ++mi)
        #pragma unroll
        for (int ni = 0; ni < 2; ++ni)
            #pragma unroll
            for (int i = 0; i < 4; ++i)
                yL[wr*32 + mi*16 + lg*4 + i][wc*32 + ni*16 + r] = acc[mi][ni][i];
    __syncthreads();

    // residual + gelu + LN2: quad of lanes per token row (4 x 16 elems)
    int rowt = tid >> 2, part = tid & 3;
    const unsigned short* zrow = Zb + ((long)(m0 + rowt))*512 + g*64 + part*16;
    s16x8 z0 = *(const s16x8*)zrow;
    s16x8 z1 = *(const s16x8*)(zrow + 8);
    const float kg = 0.7978845608028654f;
    float y[16];
    float s = 0.f, s2 = 0.f;
    #pragma unroll
    for (int q = 0; q < 16; ++q) {
        float zn = bf2f((unsigned short)(q < 8 ? z0[q] : z1[q-8]));
        float x = zn + yL[rowt][part*16 + q];
        x = 0.5f*x*(1.f + tanhf(kg*(x + 0.044715f*x*x*x)));
        y[q] = x; s += x; s2 += x*x;
    }
    s  += __shfl_xor(s,  1, 64);  s  += __shfl_xor(s,  2, 64);
    s2 += __shfl_xor(s2, 1, 64);  s2 += __shfl_xor(s2, 2, 64);
    float mu  = s * (1.f/64.f);
    float var = s2 * (1.f/64.f) - mu*mu;
    float rs  = rsqrtf(var + 1e-3f);

    int token = m0 + rowt;
    int b = token >> 11, t = token & 2047;
    long ob = (((long)(b*H + g))*T + t)*64 + part*16;
    #pragma unroll
    for (int q = 0; q < 16; ++q) {
        int f = part*16 + q;
        y[q] = g2[f]*(y[q] - mu)*rs + b2[f];
    }
    #pragma unroll
    for (int q = 0; q < 4; ++q) {
        float4 o = { y[q*4], y[q*4+1], y[q*4+2], y[q*4+3] };
        *(float4*)(out + ob + q*4) = o;
    }
}

// ---------------------------------------------------------------------------
extern "C" void kernel_launch(void* const* d_in, const int* in_sizes, int n_in,
                              void* d_out, int out_size, void* d_ws, size_t ws_size,
                              hipStream_t stream) {
    const float* emb  = (const float*)d_in[0];
    const float* keyk = (const float*)d_in[1];
    const float* qryk = (const float*)d_in[2];
    const float* valk = (const float*)d_in[3];
    const float* ffk  = (const float*)d_in[4];
    const float* g1   = (const float*)d_in[5];
    const float* b1   = (const float*)d_in[6];
    const float* g2   = (const float*)d_in[7];
    const float* b2   = (const float*)d_in[8];
    float* out = (float*)d_out;

    float* ws   = (float*)d_ws;
    float* qs   = ws;                         // 32768 floats
    float* ks   = ws + 32768;                 // 32768
    unsigned short* vT = (unsigned short*)(ws + 65568);   // 2,097,152 bf16 (1,048,576 slots)
    float* pnum = ws + 65568 + 1048576;       // 2*16*2048*64 = 4,194,304 floats
    float* pden = pnum + 4194304;             // 65,536 floats
    // Zb OVERLAYS vT: vT is dead after attn_kernel; stream order makes this
    // deterministic (qkvT writes vT -> attn reads vT -> ln1 overwrites as Zb).
    unsigned short* Zb  = vT;                 // 2,097,152 bf16
    unsigned short* WbT = (unsigned short*)(pden + 65536); // 262,144 bf16

    qkvT_kernel<<<(B*T/64)*H + H*H, 256, 0, stream>>>(emb, qryk, keyk, valk, ffk,
                                                      qs, ks, vT, WbT);
    attn_kernel<<<B*H*(T/64)*2, 256, 0, stream>>>(qs, ks, vT, pnum, pden);
    ln1_kernel<<<B*H*T/4, 256, 0, stream>>>(emb, pnum, pden, g1, b1, Zb);
    ffn_gemm_kernel<<<(B*T/64)*H, 256, 0, stream>>>(Zb, WbT, g2, b2, out);
}

// Round 26
// 64.591 us; speedup vs baseline: 1.0483x; 1.0144x over previous
//
#include <hip/hip_runtime.h>
#include <math.h>

#define T 2048
#define E 64
#define H 8
#define B 2

typedef __attribute__((ext_vector_type(4))) float f32x4;
typedef __attribute__((ext_vector_type(8))) short s16x8;

static __device__ __forceinline__ unsigned short f2bf(float x) {
    union { float f; unsigned u; } v; v.f = x;
    unsigned r = v.u + 0x7FFFu + ((v.u >> 16) & 1u);   // RNE
    return (unsigned short)(r >> 16);
}
static __device__ __forceinline__ float bf2f(unsigned short u) {
    union { unsigned u; float f; } v; v.u = ((unsigned)u) << 16;
    return v.f;
}
// packed bf16 convert: low short = lo, high short = hi (RNE, HW cvt)
static __device__ __forceinline__ unsigned pk_bf16(float lo, float hi) {
    unsigned r;
    asm("v_cvt_pk_bf16_f32 %0, %1, %2" : "=v"(r) : "v"(lo), "v"(hi));
    return r;
}

// ---------------------------------------------------------------------------
// K1 (FUSED): blocks 0..511 = qkvT (one head, 64 tokens); blocks 512..575 =
// weight transpose+cast.  (round-25 measured, unchanged)
// ---------------------------------------------------------------------------
__global__ __launch_bounds__(256) void qkvT_kernel(
    const float* __restrict__ emb,   // [B,T,E]
    const float* __restrict__ qk,    // [H,E]
    const float* __restrict__ kk,    // [H,E]
    const float* __restrict__ vk,    // [H,E,E]
    const float* __restrict__ fk,    // [H,G,E,F]
    float* __restrict__ qs,          // [B*H,T]
    float* __restrict__ ks,          // [B*H,T]
    unsigned short* __restrict__ vT, // [B*H,E(f),T] bf16
    unsigned short* __restrict__ WbT)// [512 n][512 k] bf16
{
    __shared__ __align__(16) char smem[41984];  // qkvT: eL|wkT|vtile; wcvt: wt
    int tid = threadIdx.x;

    if (blockIdx.x >= 512) {
        // ---- weight transpose+cast branch ----
        int hg = blockIdx.x - 512;       // h*8+g
        int h = hg >> 3, g = hg & 7;
        float (*wt)[65] = (float(*)[65])smem;   // 16.6 KB
        const float* src = fk + (long)hg*4096;
        #pragma unroll
        for (int j = 0; j < 4; ++j) {
            int s = tid + j*256;         // float4 slot 0..1023
            int e = s >> 4, f4 = s & 15;
            float4 v = ((const float4*)src)[s];
            wt[e][f4*4+0] = v.x; wt[e][f4*4+1] = v.y;
            wt[e][f4*4+2] = v.z; wt[e][f4*4+3] = v.w;
        }
        __syncthreads();
        #pragma unroll
        for (int j = 0; j < 2; ++j) {
            int s = tid + j*256;         // 16B slot 0..511
            int f = s >> 3, e8 = s & 7;
            s16x8 o;
            #pragma unroll
            for (int q = 0; q < 8; ++q) o[q] = (short)f2bf(wt[e8*8+q][f]);
            *(s16x8*)(WbT + ((long)(g*64+f))*512 + h*64 + e8*8) = o;
        }
        return;
    }

    // ---- qkvT branch ----
    int h  = blockIdx.x & 7;
    int tc = blockIdx.x >> 3;            // 0..63
    int b  = tc >> 5;
    int t0 = (tc & 31) * 64;

    float (*eL)[64] = (float(*)[64])smem;                         // 16 KB
    float* wkT = (float*)(smem + 16384);                          // 17.4 KB
    unsigned short* vtile = (unsigned short*)(smem + 16384 + 17408); // 8 KB

    // stage emb tile (coalesced)
    #pragma unroll
    for (int i = 0; i < 4; ++i) {
        int s = tid + i*256;             // float4 slot 0..1023
        int t = s >> 4, e4 = s & 15;
        ((float4*)&eL[t][0])[e4] = ((const float4*)(emb + ((long)b*T + t0 + t)*E))[e4];
    }
    // stage vk[h] transposed -> wkT[f][e]  (read coalesced, scatter to LDS)
    const float* vkh = vk + h*4096;
    #pragma unroll
    for (int i = 0; i < 16; ++i) {
        int s = tid + i*256;
        int e = s >> 6, f = s & 63;
        wkT[f*68 + e] = vkh[e*64 + f];
    }
    __syncthreads();

    // scores: 64 tokens x {q,k} (128 dots of 64); +t stagger spreads banks
    if (tid < 128) {
        int t = tid & 63, sel = tid >> 6;
        const float* wp = (sel ? kk : qk) + h*64;
        float s = 0.f;
        #pragma unroll
        for (int e = 0; e < 64; ++e) {
            int ei = (e + t) & 63;
            s += eL[t][ei] * wp[ei];
        }
        float* dst = sel ? ks : qs;
        dst[((long)b*H + h)*T + t0 + t] = s;
    }

    // V projection: lane f = tid&63, wave wv = tid>>6 owns t-chunks wv, wv+4
    int f  = tid & 63;
    int wv = tid >> 6;
    float acc[2][8];
    #pragma unroll
    for (int hf2 = 0; hf2 < 2; ++hf2)
        #pragma unroll
        for (int i = 0; i < 8; ++i) acc[hf2][i] = 0.f;

    #pragma unroll 4
    for (int e4 = 0; e4 < 16; ++e4) {
        float4 w4 = *(const float4*)&wkT[f*68 + e4*4];   // per-lane f: spread
        #pragma unroll
        for (int half = 0; half < 2; ++half) {
            int tb = half*32 + wv*8;
            #pragma unroll
            for (int i = 0; i < 8; ++i) {
                float4 ev = *(const float4*)&eL[tb + i][e4*4];  // wave-uniform: broadcast
                acc[half][i] += ev.x*w4.x + ev.y*w4.y + ev.z*w4.z + ev.w*w4.w;
            }
        }
    }

    // pack -> swizzled vtile (b128, conflict-free)
    #pragma unroll
    for (int half = 0; half < 2; ++half) {
        int c = wv + half*4;             // t-chunk 0..7
        s16x8 o;
        #pragma unroll
        for (int i = 0; i < 8; ++i) o[i] = (short)f2bf(acc[half][i]);
        *(s16x8*)&vtile[f*64 + ((c ^ (f & 7)) * 8)] = o;
    }
    __syncthreads();

    // coalesced writeout: 8 lanes per f-row -> 128B contiguous
    long rowbase = ((long)(b*H + h)*64) * (long)T;
    #pragma unroll
    for (int i = 0; i < 2; ++i) {
        int s = tid + i*256;             // 0..511
        int fo = s >> 3, c = s & 7;
        s16x8 v = *(const s16x8*)&vtile[fo*64 + ((c ^ (fo & 7)) * 8)];
        *(s16x8*)(vT + rowbase + (long)fo*T + t0 + c*8) = v;
    }
}

// ---------------------------------------------------------------------------
// K3: attention via MFMA with K-SPLIT=2.  THIS ROUND: XCD-aware block swizzle
// (T1) — XCD x (= blockIdx&7 under round-robin dispatch) owns bh {2x, 2x+1},
// so each vT[bh] (256 KB) is HBM-fetched into ONE XCD's L2 instead of all 8
// (32 MB -> 4 MB fetch).  Pure bijective remap: math per work item identical.
// ---------------------------------------------------------------------------
__global__ __launch_bounds__(256) void attn_kernel(
    const float* __restrict__ qs, const float* __restrict__ ksg,
    const unsigned short* __restrict__ vT,
    float* __restrict__ pnum,    // [2*16][T][64] fp32 partial numerators
    float* __restrict__ pden)    // [2*16][T] fp32 partial denominators
{
    // XCD-aware remap: xcd = bid&7, idx = bid>>3 (0..127)
    int xcd  = blockIdx.x & 7;
    int idx  = blockIdx.x >> 3;          // 0..127
    int bh   = xcd*2 + (idx >> 6);       // 0..15, contiguous per XCD
    int rest = idx & 63;
    int q0   = (rest >> 1) * 64;
    int ksp  = rest & 1;                 // k-split half
    int tid = threadIdx.x;
    int w = tid >> 6, l = tid & 63;
    int g = l >> 4, r = l & 15;

    __shared__ __align__(16) float ksL[1024];              // own half, 4 KB
    __shared__ __align__(16) unsigned short VtL[2][8192];  // 2x[64 f][128 k] swz, 32 KB
    __shared__ float sMx[4], sMn[4];

    // full-row load for GLOBAL min/max; stage only own half to LDS
    float4 k0 = ((const float4*)(ksg + (long)bh*T))[tid];        // first half
    float4 k1 = ((const float4*)(ksg + (long)bh*T))[tid + 256];  // second half
    ((float4*)ksL)[tid] = ksp ? k1 : k0;

    float mx = fmaxf(fmaxf(fmaxf(k0.x, k0.y), fmaxf(k0.z, k0.w)),
                     fmaxf(fmaxf(k1.x, k1.y), fmaxf(k1.z, k1.w)));
    float mn = fminf(fminf(fminf(k0.x, k0.y), fminf(k0.z, k0.w)),
                     fminf(fminf(k1.x, k1.y), fminf(k1.z, k1.w)));
    #pragma unroll
    for (int o = 1; o < 64; o <<= 1) {
        mx = fmaxf(mx, __shfl_xor(mx, o, 64));
        mn = fminf(mn, __shfl_xor(mn, o, 64));
    }
    if (l == 0) { sMx[w] = mx; sMn[w] = mn; }

    float sreg = qs[(long)bh*T + q0 + w*16 + r];
    int kg0 = ksp * 8;                   // global chunk base

    // prologue: stage chunk kg0 into VtL[0]
    #pragma unroll
    for (int j = 0; j < 4; ++j) {
        int i = tid + j*256;             // 16B-slot 0..1023
        int f = i >> 4, si = i & 15;
        s16x8 val = *(const s16x8*)(vT + ((long)(bh*64 + f))*T + kg0*128 + si*8);
        *(s16x8*)&VtL[0][f*128 + ((si ^ (f & 15)) * 8)] = val;
    }
    __syncthreads();                     // ksL + chunk0 + sMx/sMn visible

    float kmx = fmaxf(fmaxf(sMx[0], sMx[1]), fmaxf(sMx[2], sMx[3]));
    float kmn = fminf(fminf(sMn[0], sMn[1]), fminf(sMn[2], sMn[3]));
    float mreg = (sreg >= 0.f) ? sreg*kmx : sreg*kmn;

    f32x4 acc[4] = {{0.f,0.f,0.f,0.f},{0.f,0.f,0.f,0.f},
                    {0.f,0.f,0.f,0.f},{0.f,0.f,0.f,0.f}};
    float dsum = 0.f;

    for (int kc = 0; kc < 8; ++kc) {
        int cur = kc & 1;
        // issue prefetch loads for next chunk (latency hides under compute)
        s16x8 pf[4];
        if (kc < 7) {
            #pragma unroll
            for (int j = 0; j < 4; ++j) {
                int i = tid + j*256;
                int f = i >> 4, si = i & 15;
                pf[j] = *(const s16x8*)(vT + ((long)(bh*64 + f))*T + (kg0 + kc + 1)*128 + si*8);
            }
        }
        // compute chunk kc from VtL[cur]
        #pragma unroll
        for (int kw = 0; kw < 4; ++kw) { // 32-k MFMA windows
            int kbase = kc*128 + kw*32 + g*8;    // LOCAL ksL index
            float4 ka = *(const float4*)&ksL[kbase & 1023];
            float4 kb = *(const float4*)&ksL[(kbase & 1023) + 4];
            float p0 = __expf(fmaf(sreg, ka.x, -mreg));
            float p1 = __expf(fmaf(sreg, ka.y, -mreg));
            float p2 = __expf(fmaf(sreg, ka.z, -mreg));
            float p3 = __expf(fmaf(sreg, ka.w, -mreg));
            float p4 = __expf(fmaf(sreg, kb.x, -mreg));
            float p5 = __expf(fmaf(sreg, kb.y, -mreg));
            float p6 = __expf(fmaf(sreg, kb.z, -mreg));
            float p7 = __expf(fmaf(sreg, kb.w, -mreg));
            dsum += ((p0+p1)+(p2+p3)) + ((p4+p5)+(p6+p7));
            union { s16x8 v; unsigned u[4]; } af;
            af.u[0] = pk_bf16(p0, p1);
            af.u[1] = pk_bf16(p2, p3);
            af.u[2] = pk_bf16(p4, p5);
            af.u[3] = pk_bf16(p6, p7);
            int slot = kw*4 + g;
            #pragma unroll
            for (int ct = 0; ct < 4; ++ct) {
                s16x8 bf = *(const s16x8*)&VtL[cur][(ct*16 + r)*128 + ((slot ^ r) * 8)];
                acc[ct] = __builtin_amdgcn_mfma_f32_16x16x32_bf16(af.v, bf, acc[ct], 0, 0, 0);
            }
        }
        // write prefetched chunk to the other buffer
        if (kc < 7) {
            #pragma unroll
            for (int j = 0; j < 4; ++j) {
                int i = tid + j*256;
                int f = i >> 4, si = i & 15;
                *(s16x8*)&VtL[cur ^ 1][f*128 + ((si ^ (f & 15)) * 8)] = pf[j];
            }
        }
        __syncthreads();                 // next-chunk staging visible
    }

    // partial row-denominator: reduce over the 4 k-slot groups
    dsum += __shfl_xor(dsum, 16, 64);
    dsum += __shfl_xor(dsum, 32, 64);

    long pbase = ((long)(ksp*16 + bh)) * T;
    if (l < 16) pden[pbase + q0 + w*16 + l] = dsum;   // lane l holds row w*16+l

    #pragma unroll
    for (int i = 0; i < 4; ++i) {
        int lrow = g*4 + i;               // C layout: local row=(lane>>4)*4+i
        long q = q0 + w*16 + lrow;
        #pragma unroll
        for (int ct = 0; ct < 4; ++ct)
            pnum[(pbase + q)*64 + ct*16 + r] = acc[ct][i];
    }
}

// ---------------------------------------------------------------------------
// K4a: combine k-split partials + residual + LN1 -> Zb bf16 (GEMM layout).
// ---------------------------------------------------------------------------
__global__ __launch_bounds__(256) void ln1_kernel(
    const float* __restrict__ emb,
    const float* __restrict__ pnum, const float* __restrict__ pden,
    const float* __restrict__ g1, const float* __restrict__ b1,
    unsigned short* __restrict__ Zb) // [B*T,512] bf16
{
    int row  = blockIdx.x*4 + (threadIdx.x >> 6);  // bh*T + t, 0..32767
    int lane = threadIdx.x & 63;
    int bh = row >> 11, t = row & 2047;
    int b = bh >> 3, h = bh & 7;
    long i0 = ((long)bh)*T + t;          // split-0 row
    long i1 = ((long)(16 + bh))*T + t;   // split-1 row
    float n = pnum[i0*64 + lane] + pnum[i1*64 + lane];
    float d = pden[i0] + pden[i1];
    float x = emb[((long)b*T + t)*64 + lane] + n / d;

    float s = x, s2 = x*x;
    #pragma unroll
    for (int o = 1; o < 64; o <<= 1) {
        s  += __shfl_xor(s,  o, 64);
        s2 += __shfl_xor(s2, o, 64);
    }
    float mu  = s * (1.f/64.f);
    float var = s2 * (1.f/64.f) - mu*mu;
    float rs  = rsqrtf(var + 1e-3f);
    float zn  = g1[lane]*(x - mu)*rs + b1[lane];
    Zb[((long)b*T + t)*512 + h*64 + lane] = f2bf(zn);
}

// ---------------------------------------------------------------------------
// K4c: FFN GEMM via MFMA — double-buffered staging + smem-reuse epilogue
// (round-25 measured, unchanged).
// ---------------------------------------------------------------------------
__global__ __launch_bounds__(256) void ffn_gemm_kernel(
    const unsigned short* __restrict__ Zb,   // [4096][512] bf16
    const unsigned short* __restrict__ WbT,  // [512 n][512 k] bf16
    const float* __restrict__ g2, const float* __restrict__ b2,
    float* __restrict__ out)                 // [B,G,T,F]
{
    int bm = blockIdx.x >> 3;            // 0..63 token block
    int g  = blockIdx.x & 7;             // output head block
    int m0 = bm*64;
    int tid = threadIdx.x;
    int w = tid >> 6, l = tid & 63;
    int lg = l >> 4, r = l & 15;
    int wr = w >> 1, wc = w & 1;

    __shared__ __align__(16) char smem[32768];             // As[2]|Bs[2]; yL reuses
    unsigned short* As = (unsigned short*)smem;            // [2][4096]
    unsigned short* Bs = (unsigned short*)(smem + 16384);  // [2][4096]

    int sc16 = tid & 7;                  // staging col-chunk (fixed per thread)
    int srow0 = tid >> 3;                // staging rows (j=0: 0..31, j=1: 32..63)
    int srow1 = (tid + 256) >> 3;

    f32x4 acc[2][2] = {{{0.f,0.f,0.f,0.f},{0.f,0.f,0.f,0.f}},
                       {{0.f,0.f,0.f,0.f},{0.f,0.f,0.f,0.f}}};

    // prologue: stage kc=0 into buffer 0
    {
        s16x8 va0 = *(const s16x8*)(Zb  + ((long)(m0 + srow0))*512   + sc16*8);
        s16x8 vb0 = *(const s16x8*)(WbT + ((long)(g*64 + srow0))*512 + sc16*8);
        s16x8 va1 = *(const s16x8*)(Zb  + ((long)(m0 + srow1))*512   + sc16*8);
        s16x8 vb1 = *(const s16x8*)(WbT + ((long)(g*64 + srow1))*512 + sc16*8);
        *(s16x8*)&As[srow0*64 + ((sc16 ^ (srow0 & 7))*8)] = va0;
        *(s16x8*)&Bs[srow0*64 + ((sc16 ^ (srow0 & 7))*8)] = vb0;
        *(s16x8*)&As[srow1*64 + ((sc16 ^ (srow1 & 7))*8)] = va1;
        *(s16x8*)&Bs[srow1*64 + ((sc16 ^ (srow1 & 7))*8)] = vb1;
    }
    __syncthreads();

    for (int kc = 0; kc < 8; ++kc) {
        int cur = kc & 1;
        // prefetch next K-tile into registers (hides under compute)
        s16x8 pva0, pvb0, pva1, pvb1;
        if (kc < 7) {
            pva0 = *(const s16x8*)(Zb  + ((long)(m0 + srow0))*512   + (kc+1)*64 + sc16*8);
            pvb0 = *(const s16x8*)(WbT + ((long)(g*64 + srow0))*512 + (kc+1)*64 + sc16*8);
            pva1 = *(const s16x8*)(Zb  + ((long)(m0 + srow1))*512   + (kc+1)*64 + sc16*8);
            pvb1 = *(const s16x8*)(WbT + ((long)(g*64 + srow1))*512 + (kc+1)*64 + sc16*8);
        }
        #pragma unroll
        for (int kk = 0; kk < 2; ++kk) {
            s16x8 af[2], bf[2];
            #pragma unroll
            for (int mi = 0; mi < 2; ++mi) {
                int row = wr*32 + mi*16 + r;
                af[mi] = *(const s16x8*)&As[cur*4096 + row*64 + (((kk*4 + lg) ^ (row & 7))*8)];
            }
            #pragma unroll
            for (int ni = 0; ni < 2; ++ni) {
                int row = wc*32 + ni*16 + r;
                bf[ni] = *(const s16x8*)&Bs[cur*4096 + row*64 + (((kk*4 + lg) ^ (row & 7))*8)];
            }
            #pragma unroll
            for (int mi = 0; mi < 2; ++mi)
                #pragma unroll
                for (int ni = 0; ni < 2; ++ni)
                    acc[mi][ni] = __builtin_amdgcn_mfma_f32_16x16x32_bf16(
                        af[mi], bf[ni], acc[mi][ni], 0, 0, 0);
        }
        if (kc < 7) {
            int nb = (cur ^ 1) * 4096;
            *(s16x8*)&As[nb + srow0*64 + ((sc16 ^ (srow0 & 7))*8)] = pva0;
            *(s16x8*)&Bs[nb + srow0*64 + ((sc16 ^ (srow0 & 7))*8)] = pvb0;
            *(s16x8*)&As[nb + srow1*64 + ((sc16 ^ (srow1 & 7))*8)] = pva1;
            *(s16x8*)&Bs[nb + srow1*64 + ((sc16 ^ (srow1 & 7))*8)] = pvb1;
        }
        __syncthreads();
    }
    // all As/Bs reads complete (final barrier above) -> reuse smem as yL
    float (*yL)[68] = (float(*)[68])smem;              // 64x68 fp32, 17.4 KB

    // scatter C to yL (C layout: col=lane&15, row=(lane>>4)*4+i)
    #pragma unroll
    for (int mi = 0; mi < 2; ++mi)
        #pragma unroll
        for (int ni = 0; ni < 2; ++ni)
            #pragma unroll
            for (int i = 0; i < 4; ++i)
                yL[wr*32 + mi*16 + lg*4 + i][wc*32 + ni*16 + r] = acc[mi][ni][i];
    __syncthreads();

    // residual + gelu + LN2: quad of lanes per token row (4 x 16 elems)
    int rowt = tid >> 2, part = tid & 3;
    const unsigned short* zrow = Zb + ((long)(m0 + rowt))*512 + g*64 + part*16;
    s16x8 z0 = *(const s16x8*)zrow;
    s16x8 z1 = *(const s16x8*)(zrow + 8);
    const float kg = 0.7978845608028654f;
    float y[16];
    float s = 0.f, s2 = 0.f;
    #pragma unroll
    for (int q = 0; q < 16; ++q) {
        float zn = bf2f((unsigned short)(q < 8 ? z0[q] : z1[q-8]));
        float x = zn + yL[rowt][part*16 + q];
        x = 0.5f*x*(1.f + tanhf(kg*(x + 0.044715f*x*x*x)));
        y[q] = x; s += x; s2 += x*x;
    }
    s  += __shfl_xor(s,  1, 64);  s  += __shfl_xor(s,  2, 64);
    s2 += __shfl_xor(s2, 1, 64);  s2 += __shfl_xor(s2, 2, 64);
    float mu  = s * (1.f/64.f);
    float var = s2 * (1.f/64.f) - mu*mu;
    float rs  = rsqrtf(var + 1e-3f);

    int token = m0 + rowt;
    int b = token >> 11, t = token & 2047;
    long ob = (((long)(b*H + g))*T + t)*64 + part*16;
    #pragma unroll
    for (int q = 0; q < 16; ++q) {
        int f = part*16 + q;
        y[q] = g2[f]*(y[q] - mu)*rs + b2[f];
    }
    #pragma unroll
    for (int q = 0; q < 4; ++q) {
        float4 o = { y[q*4], y[q*4+1], y[q*4+2], y[q*4+3] };
        *(float4*)(out + ob + q*4) = o;
    }
}

// ---------------------------------------------------------------------------
extern "C" void kernel_launch(void* const* d_in, const int* in_sizes, int n_in,
                              void* d_out, int out_size, void* d_ws, size_t ws_size,
                              hipStream_t stream) {
    const float* emb  = (const float*)d_in[0];
    const float* keyk = (const float*)d_in[1];
    const float* qryk = (const float*)d_in[2];
    const float* valk = (const float*)d_in[3];
    const float* ffk  = (const float*)d_in[4];
    const float* g1   = (const float*)d_in[5];
    const float* b1   = (const float*)d_in[6];
    const float* g2   = (const float*)d_in[7];
    const float* b2   = (const float*)d_in[8];
    float* out = (float*)d_out;

    float* ws   = (float*)d_ws;
    float* qs   = ws;                         // 32768 floats
    float* ks   = ws + 32768;                 // 32768
    unsigned short* vT = (unsigned short*)(ws + 65568);   // 2,097,152 bf16 (1,048,576 slots)
    float* pnum = ws + 65568 + 1048576;       // 2*16*2048*64 = 4,194,304 floats
    float* pden = pnum + 4194304;             // 65,536 floats
    // Zb OVERLAYS vT: vT is dead after attn_kernel; stream order makes this
    // deterministic (qkvT writes vT -> attn reads vT -> ln1 overwrites as Zb).
    unsigned short* Zb  = vT;                 // 2,097,152 bf16
    unsigned short* WbT = (unsigned short*)(pden + 65536); // 262,144 bf16

    qkvT_kernel<<<(B*T/64)*H + H*H, 256, 0, stream>>>(emb, qryk, keyk, valk, ffk,
                                                      qs, ks, vT, WbT);
    attn_kernel<<<B*H*(T/64)*2, 256, 0, stream>>>(qs, ks, vT, pnum, pden);
    ln1_kernel<<<B*H*T/4, 256, 0, stream>>>(emb, pnum, pden, g1, b1, Zb);
    ffn_gemm_kernel<<<(B*T/64)*H, 256, 0, stream>>>(Zb, WbT, g2, b2, out);
}

// Round 27
// 62.438 us; speedup vs baseline: 1.0845x; 1.0345x over previous
//
#include <hip/hip_runtime.h>
#include <math.h>

#define T 2048
#define E 64
#define H 8
#define B 2

typedef __attribute__((ext_vector_type(4))) float f32x4;
typedef __attribute__((ext_vector_type(8))) short s16x8;

static __device__ __forceinline__ unsigned short f2bf(float x) {
    union { float f; unsigned u; } v; v.f = x;
    unsigned r = v.u + 0x7FFFu + ((v.u >> 16) & 1u);   // RNE
    return (unsigned short)(r >> 16);
}
static __device__ __forceinline__ float bf2f(unsigned short u) {
    union { unsigned u; float f; } v; v.u = ((unsigned)u) << 16;
    return v.f;
}
// packed bf16 convert: low short = lo, high short = hi (RNE, HW cvt)
static __device__ __forceinline__ unsigned pk_bf16(float lo, float hi) {
    unsigned r;
    asm("v_cvt_pk_bf16_f32 %0, %1, %2" : "=v"(r) : "v"(lo), "v"(hi));
    return r;
}

// ---------------------------------------------------------------------------
// K1 (FUSED): blocks 0..511 = qkvT (one head, 64 tokens); blocks 512..575 =
// weight transpose+cast.  (round-26 measured, unchanged)
// ---------------------------------------------------------------------------
__global__ __launch_bounds__(256) void qkvT_kernel(
    const float* __restrict__ emb,   // [B,T,E]
    const float* __restrict__ qk,    // [H,E]
    const float* __restrict__ kk,    // [H,E]
    const float* __restrict__ vk,    // [H,E,E]
    const float* __restrict__ fk,    // [H,G,E,F]
    float* __restrict__ qs,          // [B*H,T]
    float* __restrict__ ks,          // [B*H,T]
    unsigned short* __restrict__ vT, // [B*H,E(f),T] bf16
    unsigned short* __restrict__ WbT)// [512 n][512 k] bf16
{
    __shared__ __align__(16) char smem[41984];  // qkvT: eL|wkT|vtile; wcvt: wt
    int tid = threadIdx.x;

    if (blockIdx.x >= 512) {
        // ---- weight transpose+cast branch ----
        int hg = blockIdx.x - 512;       // h*8+g
        int h = hg >> 3, g = hg & 7;
        float (*wt)[65] = (float(*)[65])smem;   // 16.6 KB
        const float* src = fk + (long)hg*4096;
        #pragma unroll
        for (int j = 0; j < 4; ++j) {
            int s = tid + j*256;         // float4 slot 0..1023
            int e = s >> 4, f4 = s & 15;
            float4 v = ((const float4*)src)[s];
            wt[e][f4*4+0] = v.x; wt[e][f4*4+1] = v.y;
            wt[e][f4*4+2] = v.z; wt[e][f4*4+3] = v.w;
        }
        __syncthreads();
        #pragma unroll
        for (int j = 0; j < 2; ++j) {
            int s = tid + j*256;         // 16B slot 0..511
            int f = s >> 3, e8 = s & 7;
            s16x8 o;
            #pragma unroll
            for (int q = 0; q < 8; ++q) o[q] = (short)f2bf(wt[e8*8+q][f]);
            *(s16x8*)(WbT + ((long)(g*64+f))*512 + h*64 + e8*8) = o;
        }
        return;
    }

    // ---- qkvT branch ----
    int h  = blockIdx.x & 7;
    int tc = blockIdx.x >> 3;            // 0..63
    int b  = tc >> 5;
    int t0 = (tc & 31) * 64;

    float (*eL)[64] = (float(*)[64])smem;                         // 16 KB
    float* wkT = (float*)(smem + 16384);                          // 17.4 KB
    unsigned short* vtile = (unsigned short*)(smem + 16384 + 17408); // 8 KB

    // stage emb tile (coalesced)
    #pragma unroll
    for (int i = 0; i < 4; ++i) {
        int s = tid + i*256;             // float4 slot 0..1023
        int t = s >> 4, e4 = s & 15;
        ((float4*)&eL[t][0])[e4] = ((const float4*)(emb + ((long)b*T + t0 + t)*E))[e4];
    }
    // stage vk[h] transposed -> wkT[f][e]  (read coalesced, scatter to LDS)
    const float* vkh = vk + h*4096;
    #pragma unroll
    for (int i = 0; i < 16; ++i) {
        int s = tid + i*256;
        int e = s >> 6, f = s & 63;
        wkT[f*68 + e] = vkh[e*64 + f];
    }
    __syncthreads();

    // scores: 64 tokens x {q,k} (128 dots of 64); +t stagger spreads banks
    if (tid < 128) {
        int t = tid & 63, sel = tid >> 6;
        const float* wp = (sel ? kk : qk) + h*64;
        float s = 0.f;
        #pragma unroll
        for (int e = 0; e < 64; ++e) {
            int ei = (e + t) & 63;
            s += eL[t][ei] * wp[ei];
        }
        float* dst = sel ? ks : qs;
        dst[((long)b*H + h)*T + t0 + t] = s;
    }

    // V projection: lane f = tid&63, wave wv = tid>>6 owns t-chunks wv, wv+4
    int f  = tid & 63;
    int wv = tid >> 6;
    float acc[2][8];
    #pragma unroll
    for (int hf2 = 0; hf2 < 2; ++hf2)
        #pragma unroll
        for (int i = 0; i < 8; ++i) acc[hf2][i] = 0.f;

    #pragma unroll 4
    for (int e4 = 0; e4 < 16; ++e4) {
        float4 w4 = *(const float4*)&wkT[f*68 + e4*4];   // per-lane f: spread
        #pragma unroll
        for (int half = 0; half < 2; ++half) {
            int tb = half*32 + wv*8;
            #pragma unroll
            for (int i = 0; i < 8; ++i) {
                float4 ev = *(const float4*)&eL[tb + i][e4*4];  // wave-uniform: broadcast
                acc[half][i] += ev.x*w4.x + ev.y*w4.y + ev.z*w4.z + ev.w*w4.w;
            }
        }
    }

    // pack -> swizzled vtile (b128, conflict-free)
    #pragma unroll
    for (int half = 0; half < 2; ++half) {
        int c = wv + half*4;             // t-chunk 0..7
        s16x8 o;
        #pragma unroll
        for (int i = 0; i < 8; ++i) o[i] = (short)f2bf(acc[half][i]);
        *(s16x8*)&vtile[f*64 + ((c ^ (f & 7)) * 8)] = o;
    }
    __syncthreads();

    // coalesced writeout: 8 lanes per f-row -> 128B contiguous
    long rowbase = ((long)(b*H + h)*64) * (long)T;
    #pragma unroll
    for (int i = 0; i < 2; ++i) {
        int s = tid + i*256;             // 0..511
        int fo = s >> 3, c = s & 7;
        s16x8 v = *(const s16x8*)&vtile[fo*64 + ((c ^ (fo & 7)) * 8)];
        *(s16x8*)(vT + rowbase + (long)fo*T + t0 + c*8) = v;
    }
}

// ---------------------------------------------------------------------------
// K3: attention via MFMA with K-SPLIT=2 + XCD-aware swizzle (round-26
// measured, unchanged).
// ---------------------------------------------------------------------------
__global__ __launch_bounds__(256) void attn_kernel(
    const float* __restrict__ qs, const float* __restrict__ ksg,
    const unsigned short* __restrict__ vT,
    float* __restrict__ pnum,    // [2*16][T][64] fp32 partial numerators
    float* __restrict__ pden)    // [2*16][T] fp32 partial denominators
{
    // XCD-aware remap: xcd = bid&7, idx = bid>>3 (0..127)
    int xcd  = blockIdx.x & 7;
    int idx  = blockIdx.x >> 3;          // 0..127
    int bh   = xcd*2 + (idx >> 6);       // 0..15, contiguous per XCD
    int rest = idx & 63;
    int q0   = (rest >> 1) * 64;
    int ksp  = rest & 1;                 // k-split half
    int tid = threadIdx.x;
    int w = tid >> 6, l = tid & 63;
    int g = l >> 4, r = l & 15;

    __shared__ __align__(16) float ksL[1024];              // own half, 4 KB
    __shared__ __align__(16) unsigned short VtL[2][8192];  // 2x[64 f][128 k] swz, 32 KB
    __shared__ float sMx[4], sMn[4];

    // full-row load for GLOBAL min/max; stage only own half to LDS
    float4 k0 = ((const float4*)(ksg + (long)bh*T))[tid];        // first half
    float4 k1 = ((const float4*)(ksg + (long)bh*T))[tid + 256];  // second half
    ((float4*)ksL)[tid] = ksp ? k1 : k0;

    float mx = fmaxf(fmaxf(fmaxf(k0.x, k0.y), fmaxf(k0.z, k0.w)),
                     fmaxf(fmaxf(k1.x, k1.y), fmaxf(k1.z, k1.w)));
    float mn = fminf(fminf(fminf(k0.x, k0.y), fminf(k0.z, k0.w)),
                     fminf(fminf(k1.x, k1.y), fminf(k1.z, k1.w)));
    #pragma unroll
    for (int o = 1; o < 64; o <<= 1) {
        mx = fmaxf(mx, __shfl_xor(mx, o, 64));
        mn = fminf(mn, __shfl_xor(mn, o, 64));
    }
    if (l == 0) { sMx[w] = mx; sMn[w] = mn; }

    float sreg = qs[(long)bh*T + q0 + w*16 + r];
    int kg0 = ksp * 8;                   // global chunk base

    // prologue: stage chunk kg0 into VtL[0]
    #pragma unroll
    for (int j = 0; j < 4; ++j) {
        int i = tid + j*256;             // 16B-slot 0..1023
        int f = i >> 4, si = i & 15;
        s16x8 val = *(const s16x8*)(vT + ((long)(bh*64 + f))*T + kg0*128 + si*8);
        *(s16x8*)&VtL[0][f*128 + ((si ^ (f & 15)) * 8)] = val;
    }
    __syncthreads();                     // ksL + chunk0 + sMx/sMn visible

    float kmx = fmaxf(fmaxf(sMx[0], sMx[1]), fmaxf(sMx[2], sMx[3]));
    float kmn = fminf(fminf(sMn[0], sMn[1]), fminf(sMn[2], sMn[3]));
    float mreg = (sreg >= 0.f) ? sreg*kmx : sreg*kmn;

    f32x4 acc[4] = {{0.f,0.f,0.f,0.f},{0.f,0.f,0.f,0.f},
                    {0.f,0.f,0.f,0.f},{0.f,0.f,0.f,0.f}};
    float dsum = 0.f;

    for (int kc = 0; kc < 8; ++kc) {
        int cur = kc & 1;
        // issue prefetch loads for next chunk (latency hides under compute)
        s16x8 pf[4];
        if (kc < 7) {
            #pragma unroll
            for (int j = 0; j < 4; ++j) {
                int i = tid + j*256;
                int f = i >> 4, si = i & 15;
                pf[j] = *(const s16x8*)(vT + ((long)(bh*64 + f))*T + (kg0 + kc + 1)*128 + si*8);
            }
        }
        // compute chunk kc from VtL[cur]
        #pragma unroll
        for (int kw = 0; kw < 4; ++kw) { // 32-k MFMA windows
            int kbase = kc*128 + kw*32 + g*8;    // LOCAL ksL index
            float4 ka = *(const float4*)&ksL[kbase & 1023];
            float4 kb = *(const float4*)&ksL[(kbase & 1023) + 4];
            float p0 = __expf(fmaf(sreg, ka.x, -mreg));
            float p1 = __expf(fmaf(sreg, ka.y, -mreg));
            float p2 = __expf(fmaf(sreg, ka.z, -mreg));
            float p3 = __expf(fmaf(sreg, ka.w, -mreg));
            float p4 = __expf(fmaf(sreg, kb.x, -mreg));
            float p5 = __expf(fmaf(sreg, kb.y, -mreg));
            float p6 = __expf(fmaf(sreg, kb.z, -mreg));
            float p7 = __expf(fmaf(sreg, kb.w, -mreg));
            dsum += ((p0+p1)+(p2+p3)) + ((p4+p5)+(p6+p7));
            union { s16x8 v; unsigned u[4]; } af;
            af.u[0] = pk_bf16(p0, p1);
            af.u[1] = pk_bf16(p2, p3);
            af.u[2] = pk_bf16(p4, p5);
            af.u[3] = pk_bf16(p6, p7);
            int slot = kw*4 + g;
            #pragma unroll
            for (int ct = 0; ct < 4; ++ct) {
                s16x8 bf = *(const s16x8*)&VtL[cur][(ct*16 + r)*128 + ((slot ^ r) * 8)];
                acc[ct] = __builtin_amdgcn_mfma_f32_16x16x32_bf16(af.v, bf, acc[ct], 0, 0, 0);
            }
        }
        // write prefetched chunk to the other buffer
        if (kc < 7) {
            #pragma unroll
            for (int j = 0; j < 4; ++j) {
                int i = tid + j*256;
                int f = i >> 4, si = i & 15;
                *(s16x8*)&VtL[cur ^ 1][f*128 + ((si ^ (f & 15)) * 8)] = pf[j];
            }
        }
        __syncthreads();                 // next-chunk staging visible
    }

    // partial row-denominator: reduce over the 4 k-slot groups
    dsum += __shfl_xor(dsum, 16, 64);
    dsum += __shfl_xor(dsum, 32, 64);

    long pbase = ((long)(ksp*16 + bh)) * T;
    if (l < 16) pden[pbase + q0 + w*16 + l] = dsum;   // lane l holds row w*16+l

    #pragma unroll
    for (int i = 0; i < 4; ++i) {
        int lrow = g*4 + i;               // C layout: local row=(lane>>4)*4+i
        long q = q0 + w*16 + lrow;
        #pragma unroll
        for (int ct = 0; ct < 4; ++ct)
            pnum[(pbase + q)*64 + ct*16 + r] = acc[ct][i];
    }
}

// ---------------------------------------------------------------------------
// K4a: combine k-split partials + residual + LN1 -> Zb bf16 (unchanged).
// ---------------------------------------------------------------------------
__global__ __launch_bounds__(256) void ln1_kernel(
    const float* __restrict__ emb,
    const float* __restrict__ pnum, const float* __restrict__ pden,
    const float* __restrict__ g1, const float* __restrict__ b1,
    unsigned short* __restrict__ Zb) // [B*T,512] bf16
{
    int row  = blockIdx.x*4 + (threadIdx.x >> 6);  // bh*T + t, 0..32767
    int lane = threadIdx.x & 63;
    int bh = row >> 11, t = row & 2047;
    int b = bh >> 3, h = bh & 7;
    long i0 = ((long)bh)*T + t;          // split-0 row
    long i1 = ((long)(16 + bh))*T + t;   // split-1 row
    float n = pnum[i0*64 + lane] + pnum[i1*64 + lane];
    float d = pden[i0] + pden[i1];
    float x = emb[((long)b*T + t)*64 + lane] + n / d;

    float s = x, s2 = x*x;
    #pragma unroll
    for (int o = 1; o < 64; o <<= 1) {
        s  += __shfl_xor(s,  o, 64);
        s2 += __shfl_xor(s2, o, 64);
    }
    float mu  = s * (1.f/64.f);
    float var = s2 * (1.f/64.f) - mu*mu;
    float rs  = rsqrtf(var + 1e-3f);
    float zn  = g1[lane]*(x - mu)*rs + b1[lane];
    Zb[((long)b*T + t)*512 + h*64 + lane] = f2bf(zn);
}

// ---------------------------------------------------------------------------
// K4c: FFN GEMM via MFMA — M-SPLIT (this round): BM=32 -> grid 1024 = 4
// blocks/CU (was 512 = 2/CU).  Full K per block -> per-element MFMA
// accumulation order unchanged (C bit-identical).  Double-buffered staging
// + smem-reuse epilogue kept.  LN2 epilogue uses width-8 lane groups.
// ---------------------------------------------------------------------------
__global__ __launch_bounds__(256) void ffn_gemm_kernel(
    const unsigned short* __restrict__ Zb,   // [4096][512] bf16
    const unsigned short* __restrict__ WbT,  // [512 n][512 k] bf16
    const float* __restrict__ g2, const float* __restrict__ b2,
    float* __restrict__ out)                 // [B,G,T,F]
{
    int bm = blockIdx.x >> 3;            // 0..127 token block (32 tokens)
    int g  = blockIdx.x & 7;             // output head block
    int m0 = bm*32;
    int tid = threadIdx.x;
    int w = tid >> 6, l = tid & 63;
    int lg = l >> 4, r = l & 15;
    int wr = w >> 1, wc = w & 1;         // wave tile: 16 m-rows x 32 n-cols

    __shared__ __align__(16) char smem[24576];   // As[2](4KB ea)|Bs[2](8KB ea); yL reuses
    unsigned short* As = (unsigned short*)smem;            // [2][2048]
    unsigned short* Bs = (unsigned short*)(smem + 8192);   // [2][4096]

    int sc16  = tid & 7;                 // staging col-chunk
    int arow  = tid >> 3;                // A row 0..31
    int brow0 = tid >> 3;                // B rows 0..31 (j=0)
    int brow1 = (tid + 256) >> 3;        // B rows 32..63 (j=1)

    f32x4 acc[2] = {{0.f,0.f,0.f,0.f},{0.f,0.f,0.f,0.f}};

    // prologue: stage kc=0 into buffer 0
    {
        s16x8 va  = *(const s16x8*)(Zb  + ((long)(m0 + arow))*512    + sc16*8);
        s16x8 vb0 = *(const s16x8*)(WbT + ((long)(g*64 + brow0))*512 + sc16*8);
        s16x8 vb1 = *(const s16x8*)(WbT + ((long)(g*64 + brow1))*512 + sc16*8);
        *(s16x8*)&As[arow*64  + ((sc16 ^ (arow  & 7))*8)] = va;
        *(s16x8*)&Bs[brow0*64 + ((sc16 ^ (brow0 & 7))*8)] = vb0;
        *(s16x8*)&Bs[brow1*64 + ((sc16 ^ (brow1 & 7))*8)] = vb1;
    }
    __syncthreads();

    for (int kc = 0; kc < 8; ++kc) {
        int cur = kc & 1;
        // prefetch next K-tile into registers (hides under compute)
        s16x8 pva, pvb0, pvb1;
        if (kc < 7) {
            pva  = *(const s16x8*)(Zb  + ((long)(m0 + arow))*512    + (kc+1)*64 + sc16*8);
            pvb0 = *(const s16x8*)(WbT + ((long)(g*64 + brow0))*512 + (kc+1)*64 + sc16*8);
            pvb1 = *(const s16x8*)(WbT + ((long)(g*64 + brow1))*512 + (kc+1)*64 + sc16*8);
        }
        #pragma unroll
        for (int kk = 0; kk < 2; ++kk) {
            int rowA = wr*16 + r;
            s16x8 af = *(const s16x8*)&As[cur*2048 + rowA*64 + (((kk*4 + lg) ^ (rowA & 7))*8)];
            s16x8 bf[2];
            #pragma unroll
            for (int ni = 0; ni < 2; ++ni) {
                int rowB = wc*32 + ni*16 + r;
                bf[ni] = *(const s16x8*)&Bs[cur*4096 + rowB*64 + (((kk*4 + lg) ^ (rowB & 7))*8)];
            }
            #pragma unroll
            for (int ni = 0; ni < 2; ++ni)
                acc[ni] = __builtin_amdgcn_mfma_f32_16x16x32_bf16(af, bf[ni], acc[ni], 0, 0, 0);
        }
        if (kc < 7) {
            *(s16x8*)&As[(cur^1)*2048 + arow*64  + ((sc16 ^ (arow  & 7))*8)] = pva;
            *(s16x8*)&Bs[(cur^1)*4096 + brow0*64 + ((sc16 ^ (brow0 & 7))*8)] = pvb0;
            *(s16x8*)&Bs[(cur^1)*4096 + brow1*64 + ((sc16 ^ (brow1 & 7))*8)] = pvb1;
        }
        __syncthreads();
    }
    // all As/Bs reads complete (final barrier above) -> reuse smem as yL
    float (*yL)[68] = (float(*)[68])smem;              // 32x68 fp32, 8.7 KB

    // scatter C to yL (C layout: col=lane&15, row=(lane>>4)*4+i)
    #pragma unroll
    for (int ni = 0; ni < 2; ++ni)
        #pragma unroll
        for (int i = 0; i < 4; ++i)
            yL[wr*16 + lg*4 + i][wc*32 + ni*16 + r] = acc[ni][i];
    __syncthreads();

    // residual + gelu + LN2: 8 lanes per token row (8 x 8 elems)
    int rowt = tid >> 3, part = tid & 7;
    const unsigned short* zrow = Zb + ((long)(m0 + rowt))*512 + g*64 + part*8;
    s16x8 z0 = *(const s16x8*)zrow;
    const float kg = 0.7978845608028654f;
    float y[8];
    float s = 0.f, s2 = 0.f;
    #pragma unroll
    for (int q = 0; q < 8; ++q) {
        float zn = bf2f((unsigned short)z0[q]);
        float x = zn + yL[rowt][part*8 + q];
        x = 0.5f*x*(1.f + tanhf(kg*(x + 0.044715f*x*x*x)));
        y[q] = x; s += x; s2 += x*x;
    }
    s  += __shfl_xor(s,  1, 8);  s  += __shfl_xor(s,  2, 8);  s  += __shfl_xor(s,  4, 8);
    s2 += __shfl_xor(s2, 1, 8);  s2 += __shfl_xor(s2, 2, 8);  s2 += __shfl_xor(s2, 4, 8);
    float mu  = s * (1.f/64.f);
    float var = s2 * (1.f/64.f) - mu*mu;
    float rs  = rsqrtf(var + 1e-3f);

    int token = m0 + rowt;
    int b = token >> 11, t = token & 2047;
    long ob = (((long)(b*H + g))*T + t)*64 + part*8;
    #pragma unroll
    for (int q = 0; q < 8; ++q) {
        int f = part*8 + q;
        y[q] = g2[f]*(y[q] - mu)*rs + b2[f];
    }
    #pragma unroll
    for (int q = 0; q < 2; ++q) {
        float4 o = { y[q*4], y[q*4+1], y[q*4+2], y[q*4+3] };
        *(float4*)(out + ob + q*4) = o;
    }
}

// ---------------------------------------------------------------------------
extern "C" void kernel_launch(void* const* d_in, const int* in_sizes, int n_in,
                              void* d_out, int out_size, void* d_ws, size_t ws_size,
                              hipStream_t stream) {
    const float* emb  = (const float*)d_in[0];
    const float* keyk = (const float*)d_in[1];
    const float* qryk = (const float*)d_in[2];
    const float* valk = (const float*)d_in[3];
    const float* ffk  = (const float*)d_in[4];
    const float* g1   = (const float*)d_in[5];
    const float* b1   = (const float*)d_in[6];
    const float* g2   = (const float*)d_in[7];
    const float* b2   = (const float*)d_in[8];
    float* out = (float*)d_out;

    float* ws   = (float*)d_ws;
    float* qs   = ws;                         // 32768 floats
    float* ks   = ws + 32768;                 // 32768
    unsigned short* vT = (unsigned short*)(ws + 65568);   // 2,097,152 bf16 (1,048,576 slots)
    float* pnum = ws + 65568 + 1048576;       // 2*16*2048*64 = 4,194,304 floats
    float* pden = pnum + 4194304;             // 65,536 floats
    // Zb OVERLAYS vT: vT is dead after attn_kernel; stream order makes this
    // deterministic (qkvT writes vT -> attn reads vT -> ln1 overwrites as Zb).
    unsigned short* Zb  = vT;                 // 2,097,152 bf16
    unsigned short* WbT = (unsigned short*)(pden + 65536); // 262,144 bf16

    qkvT_kernel<<<(B*T/64)*H + H*H, 256, 0, stream>>>(emb, qryk, keyk, valk, ffk,
                                                      qs, ks, vT, WbT);
    attn_kernel<<<B*H*(T/64)*2, 256, 0, stream>>>(qs, ks, vT, pnum, pden);
    ln1_kernel<<<B*H*T/4, 256, 0, stream>>>(emb, pnum, pden, g1, b1, Zb);
    ffn_gemm_kernel<<<(B*T/32)*H, 256, 0, stream>>>(Zb, WbT, g2, b2, out);
}

// Round 28
// 58.979 us; speedup vs baseline: 1.1481x; 1.0586x over previous
//
#include <hip/hip_runtime.h>
#include <math.h>

#define T 2048
#define E 64
#define H 8
#define B 2

typedef __attribute__((ext_vector_type(4))) float f32x4;
typedef __attribute__((ext_vector_type(8))) short s16x8;

static __device__ __forceinline__ unsigned short f2bf(float x) {
    union { float f; unsigned u; } v; v.f = x;
    unsigned r = v.u + 0x7FFFu + ((v.u >> 16) & 1u);   // RNE
    return (unsigned short)(r >> 16);
}
static __device__ __forceinline__ float bf2f(unsigned short u) {
    union { unsigned u; float f; } v; v.u = ((unsigned)u) << 16;
    return v.f;
}
// packed bf16 convert: low short = lo, high short = hi (RNE, HW cvt)
static __device__ __forceinline__ unsigned pk_bf16(float lo, float hi) {
    unsigned r;
    asm("v_cvt_pk_bf16_f32 %0, %1, %2" : "=v"(r) : "v"(lo), "v"(hi));
    return r;
}

// ---------------------------------------------------------------------------
// K1 (FUSED, T-SPLIT this round): blocks 0..1023 = qkvT (one head, 32 tokens
// -> ~4.25 blocks/CU, LDS 29 KB); blocks 1024..1087 = weight transpose+cast.
// Per-output-element math identical to round-27 -> bit-identical results.
// ---------------------------------------------------------------------------
__global__ __launch_bounds__(256) void qkvT_kernel(
    const float* __restrict__ emb,   // [B,T,E]
    const float* __restrict__ qk,    // [H,E]
    const float* __restrict__ kk,    // [H,E]
    const float* __restrict__ vk,    // [H,E,E]
    const float* __restrict__ fk,    // [H,G,E,F]
    float* __restrict__ qs,          // [B*H,T]
    float* __restrict__ ks,          // [B*H,T]
    unsigned short* __restrict__ vT, // [B*H,E(f),T] bf16
    unsigned short* __restrict__ WbT)// [512 n][512 k] bf16
{
    __shared__ __align__(16) char smem[29696];  // qkvT: eL|wkT|vtile; wcvt: wt
    int tid = threadIdx.x;

    if (blockIdx.x >= 1024) {
        // ---- weight transpose+cast branch ----
        int hg = blockIdx.x - 1024;      // h*8+g
        int h = hg >> 3, g = hg & 7;
        float (*wt)[65] = (float(*)[65])smem;   // 16.6 KB
        const float* src = fk + (long)hg*4096;
        #pragma unroll
        for (int j = 0; j < 4; ++j) {
            int s = tid + j*256;         // float4 slot 0..1023
            int e = s >> 4, f4 = s & 15;
            float4 v = ((const float4*)src)[s];
            wt[e][f4*4+0] = v.x; wt[e][f4*4+1] = v.y;
            wt[e][f4*4+2] = v.z; wt[e][f4*4+3] = v.w;
        }
        __syncthreads();
        #pragma unroll
        for (int j = 0; j < 2; ++j) {
            int s = tid + j*256;         // 16B slot 0..511
            int f = s >> 3, e8 = s & 7;
            s16x8 o;
            #pragma unroll
            for (int q = 0; q < 8; ++q) o[q] = (short)f2bf(wt[e8*8+q][f]);
            *(s16x8*)(WbT + ((long)(g*64+f))*512 + h*64 + e8*8) = o;
        }
        return;
    }

    // ---- qkvT branch: one head, 32 tokens ----
    int h  = blockIdx.x & 7;
    int tc = blockIdx.x >> 3;            // 0..127
    int b  = tc >> 6;
    int t0 = (tc & 63) * 32;

    float (*eL)[64] = (float(*)[64])smem;                         // 8 KB
    float* wkT = (float*)(smem + 8192);                           // 17.4 KB
    unsigned short* vtile = (unsigned short*)(smem + 8192 + 17408); // 4 KB

    // stage emb tile (coalesced): 32 tokens x 64 = 512 float4 slots
    #pragma unroll
    for (int i = 0; i < 2; ++i) {
        int s = tid + i*256;             // float4 slot 0..511
        int t = s >> 4, e4 = s & 15;
        ((float4*)&eL[t][0])[e4] = ((const float4*)(emb + ((long)b*T + t0 + t)*E))[e4];
    }
    // stage vk[h] transposed -> wkT[f][e]  (read coalesced, scatter to LDS)
    const float* vkh = vk + h*4096;
    #pragma unroll
    for (int i = 0; i < 16; ++i) {
        int s = tid + i*256;
        int e = s >> 6, f = s & 63;
        wkT[f*68 + e] = vkh[e*64 + f];
    }
    __syncthreads();

    // scores: 32 tokens x {q,k} (64 dots of 64); +t stagger spreads banks
    if (tid < 64) {
        int t = tid & 31, sel = tid >> 5;
        const float* wp = (sel ? kk : qk) + h*64;
        float s = 0.f;
        #pragma unroll
        for (int e = 0; e < 64; ++e) {
            int ei = (e + t) & 63;
            s += eL[t][ei] * wp[ei];
        }
        float* dst = sel ? ks : qs;
        dst[((long)b*H + h)*T + t0 + t] = s;
    }

    // V projection: lane f = tid&63, wave wv = tid>>6 owns t-chunk wv (8 tok)
    int f  = tid & 63;
    int wv = tid >> 6;
    float acc[8];
    #pragma unroll
    for (int i = 0; i < 8; ++i) acc[i] = 0.f;

    #pragma unroll 4
    for (int e4 = 0; e4 < 16; ++e4) {
        float4 w4 = *(const float4*)&wkT[f*68 + e4*4];   // per-lane f: spread
        int tb = wv*8;
        #pragma unroll
        for (int i = 0; i < 8; ++i) {
            float4 ev = *(const float4*)&eL[tb + i][e4*4];  // wave-uniform: broadcast
            acc[i] += ev.x*w4.x + ev.y*w4.y + ev.z*w4.z + ev.w*w4.w;
        }
    }

    // pack -> swizzled vtile [64 f][32 t] (b128)
    {
        int c = wv;                      // t-chunk 0..3
        s16x8 o;
        #pragma unroll
        for (int i = 0; i < 8; ++i) o[i] = (short)f2bf(acc[i]);
        *(s16x8*)&vtile[f*32 + ((c ^ (f & 3)) * 8)] = o;
    }
    __syncthreads();

    // coalesced writeout: 4 lanes per f-row -> 64B contiguous
    long rowbase = ((long)(b*H + h)*64) * (long)T;
    {
        int s = tid;                     // 0..255
        int fo = s >> 2, c = s & 3;
        s16x8 v = *(const s16x8*)&vtile[fo*32 + ((c ^ (fo & 3)) * 8)];
        *(s16x8*)(vT + rowbase + (long)fo*T + t0 + c*8) = v;
    }
}

// ---------------------------------------------------------------------------
// K3: attention via MFMA with K-SPLIT=2 + XCD-aware swizzle (round-27
// measured, unchanged).
// ---------------------------------------------------------------------------
__global__ __launch_bounds__(256) void attn_kernel(
    const float* __restrict__ qs, const float* __restrict__ ksg,
    const unsigned short* __restrict__ vT,
    float* __restrict__ pnum,    // [2*16][T][64] fp32 partial numerators
    float* __restrict__ pden)    // [2*16][T] fp32 partial denominators
{
    // XCD-aware remap: xcd = bid&7, idx = bid>>3 (0..127)
    int xcd  = blockIdx.x & 7;
    int idx  = blockIdx.x >> 3;          // 0..127
    int bh   = xcd*2 + (idx >> 6);       // 0..15, contiguous per XCD
    int rest = idx & 63;
    int q0   = (rest >> 1) * 64;
    int ksp  = rest & 1;                 // k-split half
    int tid = threadIdx.x;
    int w = tid >> 6, l = tid & 63;
    int g = l >> 4, r = l & 15;

    __shared__ __align__(16) float ksL[1024];              // own half, 4 KB
    __shared__ __align__(16) unsigned short VtL[2][8192];  // 2x[64 f][128 k] swz, 32 KB
    __shared__ float sMx[4], sMn[4];

    // full-row load for GLOBAL min/max; stage only own half to LDS
    float4 k0 = ((const float4*)(ksg + (long)bh*T))[tid];        // first half
    float4 k1 = ((const float4*)(ksg + (long)bh*T))[tid + 256];  // second half
    ((float4*)ksL)[tid] = ksp ? k1 : k0;

    float mx = fmaxf(fmaxf(fmaxf(k0.x, k0.y), fmaxf(k0.z, k0.w)),
                     fmaxf(fmaxf(k1.x, k1.y), fmaxf(k1.z, k1.w)));
    float mn = fminf(fminf(fminf(k0.x, k0.y), fminf(k0.z, k0.w)),
                     fminf(fminf(k1.x, k1.y), fminf(k1.z, k1.w)));
    #pragma unroll
    for (int o = 1; o < 64; o <<= 1) {
        mx = fmaxf(mx, __shfl_xor(mx, o, 64));
        mn = fminf(mn, __shfl_xor(mn, o, 64));
    }
    if (l == 0) { sMx[w] = mx; sMn[w] = mn; }

    float sreg = qs[(long)bh*T + q0 + w*16 + r];
    int kg0 = ksp * 8;                   // global chunk base

    // prologue: stage chunk kg0 into VtL[0]
    #pragma unroll
    for (int j = 0; j < 4; ++j) {
        int i = tid + j*256;             // 16B-slot 0..1023
        int f = i >> 4, si = i & 15;
        s16x8 val = *(const s16x8*)(vT + ((long)(bh*64 + f))*T + kg0*128 + si*8);
        *(s16x8*)&VtL[0][f*128 + ((si ^ (f & 15)) * 8)] = val;
    }
    __syncthreads();                     // ksL + chunk0 + sMx/sMn visible

    float kmx = fmaxf(fmaxf(sMx[0], sMx[1]), fmaxf(sMx[2], sMx[3]));
    float kmn = fminf(fminf(sMn[0], sMn[1]), fminf(sMn[2], sMn[3]));
    float mreg = (sreg >= 0.f) ? sreg*kmx : sreg*kmn;

    f32x4 acc[4] = {{0.f,0.f,0.f,0.f},{0.f,0.f,0.f,0.f},
                    {0.f,0.f,0.f,0.f},{0.f,0.f,0.f,0.f}};
    float dsum = 0.f;

    for (int kc = 0; kc < 8; ++kc) {
        int cur = kc & 1;
        // issue prefetch loads for next chunk (latency hides under compute)
        s16x8 pf[4];
        if (kc < 7) {
            #pragma unroll
            for (int j = 0; j < 4; ++j) {
                int i = tid + j*256;
                int f = i >> 4, si = i & 15;
                pf[j] = *(const s16x8*)(vT + ((long)(bh*64 + f))*T + (kg0 + kc + 1)*128 + si*8);
            }
        }
        // compute chunk kc from VtL[cur]
        #pragma unroll
        for (int kw = 0; kw < 4; ++kw) { // 32-k MFMA windows
            int kbase = kc*128 + kw*32 + g*8;    // LOCAL ksL index
            float4 ka = *(const float4*)&ksL[kbase & 1023];
            float4 kb = *(const float4*)&ksL[(kbase & 1023) + 4];
            float p0 = __expf(fmaf(sreg, ka.x, -mreg));
            float p1 = __expf(fmaf(sreg, ka.y, -mreg));
            float p2 = __expf(fmaf(sreg, ka.z, -mreg));
            float p3 = __expf(fmaf(sreg, ka.w, -mreg));
            float p4 = __expf(fmaf(sreg, kb.x, -mreg));
            float p5 = __expf(fmaf(sreg, kb.y, -mreg));
            float p6 = __expf(fmaf(sreg, kb.z, -mreg));
            float p7 = __expf(fmaf(sreg, kb.w, -mreg));
            dsum += ((p0+p1)+(p2+p3)) + ((p4+p5)+(p6+p7));
            union { s16x8 v; unsigned u[4]; } af;
            af.u[0] = pk_bf16(p0, p1);
            af.u[1] = pk_bf16(p2, p3);
            af.u[2] = pk_bf16(p4, p5);
            af.u[3] = pk_bf16(p6, p7);
            int slot = kw*4 + g;
            #pragma unroll
            for (int ct = 0; ct < 4; ++ct) {
                s16x8 bf = *(const s16x8*)&VtL[cur][(ct*16 + r)*128 + ((slot ^ r) * 8)];
                acc[ct] = __builtin_amdgcn_mfma_f32_16x16x32_bf16(af.v, bf, acc[ct], 0, 0, 0);
            }
        }
        // write prefetched chunk to the other buffer
        if (kc < 7) {
            #pragma unroll
            for (int j = 0; j < 4; ++j) {
                int i = tid + j*256;
                int f = i >> 4, si = i & 15;
                *(s16x8*)&VtL[cur ^ 1][f*128 + ((si ^ (f & 15)) * 8)] = pf[j];
            }
        }
        __syncthreads();                 // next-chunk staging visible
    }

    // partial row-denominator: reduce over the 4 k-slot groups
    dsum += __shfl_xor(dsum, 16, 64);
    dsum += __shfl_xor(dsum, 32, 64);

    long pbase = ((long)(ksp*16 + bh)) * T;
    if (l < 16) pden[pbase + q0 + w*16 + l] = dsum;   // lane l holds row w*16+l

    #pragma unroll
    for (int i = 0; i < 4; ++i) {
        int lrow = g*4 + i;               // C layout: local row=(lane>>4)*4+i
        long q = q0 + w*16 + lrow;
        #pragma unroll
        for (int ct = 0; ct < 4; ++ct)
            pnum[(pbase + q)*64 + ct*16 + r] = acc[ct][i];
    }
}

// ---------------------------------------------------------------------------
// K4a: combine k-split partials + residual + LN1 -> Zb bf16 (unchanged).
// ---------------------------------------------------------------------------
__global__ __launch_bounds__(256) void ln1_kernel(
    const float* __restrict__ emb,
    const float* __restrict__ pnum, const float* __restrict__ pden,
    const float* __restrict__ g1, const float* __restrict__ b1,
    unsigned short* __restrict__ Zb) // [B*T,512] bf16
{
    int row  = blockIdx.x*4 + (threadIdx.x >> 6);  // bh*T + t, 0..32767
    int lane = threadIdx.x & 63;
    int bh = row >> 11, t = row & 2047;
    int b = bh >> 3, h = bh & 7;
    long i0 = ((long)bh)*T + t;          // split-0 row
    long i1 = ((long)(16 + bh))*T + t;   // split-1 row
    float n = pnum[i0*64 + lane] + pnum[i1*64 + lane];
    float d = pden[i0] + pden[i1];
    float x = emb[((long)b*T + t)*64 + lane] + n / d;

    float s = x, s2 = x*x;
    #pragma unroll
    for (int o = 1; o < 64; o <<= 1) {
        s  += __shfl_xor(s,  o, 64);
        s2 += __shfl_xor(s2, o, 64);
    }
    float mu  = s * (1.f/64.f);
    float var = s2 * (1.f/64.f) - mu*mu;
    float rs  = rsqrtf(var + 1e-3f);
    float zn  = g1[lane]*(x - mu)*rs + b1[lane];
    Zb[((long)b*T + t)*512 + h*64 + lane] = f2bf(zn);
}

// ---------------------------------------------------------------------------
// K4c: FFN GEMM via MFMA — m-split BM=32, double-buffered staging, smem-reuse
// epilogue (round-27 measured, unchanged).
// ---------------------------------------------------------------------------
__global__ __launch_bounds__(256) void ffn_gemm_kernel(
    const unsigned short* __restrict__ Zb,   // [4096][512] bf16
    const unsigned short* __restrict__ WbT,  // [512 n][512 k] bf16
    const float* __restrict__ g2, const float* __restrict__ b2,
    float* __restrict__ out)                 // [B,G,T,F]
{
    int bm = blockIdx.x >> 3;            // 0..127 token block (32 tokens)
    int g  = blockIdx.x & 7;             // output head block
    int m0 = bm*32;
    int tid = threadIdx.x;
    int w = tid >> 6, l = tid & 63;
    int lg = l >> 4, r = l & 15;
    int wr = w >> 1, wc = w & 1;         // wave tile: 16 m-rows x 32 n-cols

    __shared__ __align__(16) char smem[24576];   // As[2](4KB ea)|Bs[2](8KB ea); yL reuses
    unsigned short* As = (unsigned short*)smem;            // [2][2048]
    unsigned short* Bs = (unsigned short*)(smem + 8192);   // [2][4096]

    int sc16  = tid & 7;                 // staging col-chunk
    int arow  = tid >> 3;                // A row 0..31
    int brow0 = tid >> 3;                // B rows 0..31 (j=0)
    int brow1 = (tid + 256) >> 3;        // B rows 32..63 (j=1)

    f32x4 acc[2] = {{0.f,0.f,0.f,0.f},{0.f,0.f,0.f,0.f}};

    // prologue: stage kc=0 into buffer 0
    {
        s16x8 va  = *(const s16x8*)(Zb  + ((long)(m0 + arow))*512    + sc16*8);
        s16x8 vb0 = *(const s16x8*)(WbT + ((long)(g*64 + brow0))*512 + sc16*8);
        s16x8 vb1 = *(const s16x8*)(WbT + ((long)(g*64 + brow1))*512 + sc16*8);
        *(s16x8*)&As[arow*64  + ((sc16 ^ (arow  & 7))*8)] = va;
        *(s16x8*)&Bs[brow0*64 + ((sc16 ^ (brow0 & 7))*8)] = vb0;
        *(s16x8*)&Bs[brow1*64 + ((sc16 ^ (brow1 & 7))*8)] = vb1;
    }
    __syncthreads();

    for (int kc = 0; kc < 8; ++kc) {
        int cur = kc & 1;
        // prefetch next K-tile into registers (hides under compute)
        s16x8 pva, pvb0, pvb1;
        if (kc < 7) {
            pva  = *(const s16x8*)(Zb  + ((long)(m0 + arow))*512    + (kc+1)*64 + sc16*8);
            pvb0 = *(const s16x8*)(WbT + ((long)(g*64 + brow0))*512 + (kc+1)*64 + sc16*8);
            pvb1 = *(const s16x8*)(WbT + ((long)(g*64 + brow1))*512 + (kc+1)*64 + sc16*8);
        }
        #pragma unroll
        for (int kk = 0; kk < 2; ++kk) {
            int rowA = wr*16 + r;
            s16x8 af = *(const s16x8*)&As[cur*2048 + rowA*64 + (((kk*4 + lg) ^ (rowA & 7))*8)];
            s16x8 bf[2];
            #pragma unroll
            for (int ni = 0; ni < 2; ++ni) {
                int rowB = wc*32 + ni*16 + r;
                bf[ni] = *(const s16x8*)&Bs[cur*4096 + rowB*64 + (((kk*4 + lg) ^ (rowB & 7))*8)];
            }
            #pragma unroll
            for (int ni = 0; ni < 2; ++ni)
                acc[ni] = __builtin_amdgcn_mfma_f32_16x16x32_bf16(af, bf[ni], acc[ni], 0, 0, 0);
        }
        if (kc < 7) {
            *(s16x8*)&As[(cur^1)*2048 + arow*64  + ((sc16 ^ (arow  & 7))*8)] = pva;
            *(s16x8*)&Bs[(cur^1)*4096 + brow0*64 + ((sc16 ^ (brow0 & 7))*8)] = pvb0;
            *(s16x8*)&Bs[(cur^1)*4096 + brow1*64 + ((sc16 ^ (brow1 & 7))*8)] = pvb1;
        }
        __syncthreads();
    }
    // all As/Bs reads complete (final barrier above) -> reuse smem as yL
    float (*yL)[68] = (float(*)[68])smem;              // 32x68 fp32, 8.7 KB

    // scatter C to yL (C layout: col=lane&15, row=(lane>>4)*4+i)
    #pragma unroll
    for (int ni = 0; ni < 2; ++ni)
        #pragma unroll
        for (int i = 0; i < 4; ++i)
            yL[wr*16 + lg*4 + i][wc*32 + ni*16 + r] = acc[ni][i];
    __syncthreads();

    // residual + gelu + LN2: 8 lanes per token row (8 x 8 elems)
    int rowt = tid >> 3, part = tid & 7;
    const unsigned short* zrow = Zb + ((long)(m0 + rowt))*512 + g*64 + part*8;
    s16x8 z0 = *(const s16x8*)zrow;
    const float kg = 0.7978845608028654f;
    float y[8];
    float s = 0.f, s2 = 0.f;
    #pragma unroll
    for (int q = 0; q < 8; ++q) {
        float zn = bf2f((unsigned short)z0[q]);
        float x = zn + yL[rowt][part*8 + q];
        x = 0.5f*x*(1.f + tanhf(kg*(x + 0.044715f*x*x*x)));
        y[q] = x; s += x; s2 += x*x;
    }
    s  += __shfl_xor(s,  1, 8);  s  += __shfl_xor(s,  2, 8);  s  += __shfl_xor(s,  4, 8);
    s2 += __shfl_xor(s2, 1, 8);  s2 += __shfl_xor(s2, 2, 8);  s2 += __shfl_xor(s2, 4, 8);
    float mu  = s * (1.f/64.f);
    float var = s2 * (1.f/64.f) - mu*mu;
    float rs  = rsqrtf(var + 1e-3f);

    int token = m0 + rowt;
    int b = token >> 11, t = token & 2047;
    long ob = (((long)(b*H + g))*T + t)*64 + part*8;
    #pragma unroll
    for (int q = 0; q < 8; ++q) {
        int f = part*8 + q;
        y[q] = g2[f]*(y[q] - mu)*rs + b2[f];
    }
    #pragma unroll
    for (int q = 0; q < 2; ++q) {
        float4 o = { y[q*4], y[q*4+1], y[q*4+2], y[q*4+3] };
        *(float4*)(out + ob + q*4) = o;
    }
}

// ---------------------------------------------------------------------------
extern "C" void kernel_launch(void* const* d_in, const int* in_sizes, int n_in,
                              void* d_out, int out_size, void* d_ws, size_t ws_size,
                              hipStream_t stream) {
    const float* emb  = (const float*)d_in[0];
    const float* keyk = (const float*)d_in[1];
    const float* qryk = (const float*)d_in[2];
    const float* valk = (const float*)d_in[3];
    const float* ffk  = (const float*)d_in[4];
    const float* g1   = (const float*)d_in[5];
    const float* b1   = (const float*)d_in[6];
    const float* g2   = (const float*)d_in[7];
    const float* b2   = (const float*)d_in[8];
    float* out = (float*)d_out;

    float* ws   = (float*)d_ws;
    float* qs   = ws;                         // 32768 floats
    float* ks   = ws + 32768;                 // 32768
    unsigned short* vT = (unsigned short*)(ws + 65568);   // 2,097,152 bf16 (1,048,576 slots)
    float* pnum = ws + 65568 + 1048576;       // 2*16*2048*64 = 4,194,304 floats
    float* pden = pnum + 4194304;             // 65,536 floats
    // Zb OVERLAYS vT: vT is dead after attn_kernel; stream order makes this
    // deterministic (qkvT writes vT -> attn reads vT -> ln1 overwrites as Zb).
    unsigned short* Zb  = vT;                 // 2,097,152 bf16
    unsigned short* WbT = (unsigned short*)(pden + 65536); // 262,144 bf16

    qkvT_kernel<<<(B*T/32)*H + H*H, 256, 0, stream>>>(emb, qryk, keyk, valk, ffk,
                                                      qs, ks, vT, WbT);
    attn_kernel<<<B*H*(T/64)*2, 256, 0, stream>>>(qs, ks, vT, pnum, pden);
    ln1_kernel<<<B*H*T/4, 256, 0, stream>>>(emb, pnum, pden, g1, b1, Zb);
    ffn_gemm_kernel<<<(B*T/32)*H, 256, 0, stream>>>(Zb, WbT, g2, b2, out);
}